// Round 11
// baseline (177.225 us; speedup 1.0000x reference)
//
#include <hip/hip_runtime.h>
#include <math.h>

typedef __bf16 bf16x8 __attribute__((ext_vector_type(8)));
typedef float f32x4 __attribute__((ext_vector_type(4)));
typedef float f32x16 __attribute__((ext_vector_type(16)));
typedef unsigned short u16;
typedef unsigned short u16x4 __attribute__((ext_vector_type(4)));

#define BB 2
#define TT 2048
#define EE 768
#define HH 12
#define DD 64
#define BH (BB*HH)      /* 24 */
#define M4 (BB*TT)      /* 4096 */
#define NQKV (3*EE)     /* 2304 */
#define SCH 16          /* scan chunks (128 t each) */
#define KSEG 512        /* flash split-K segment */
#define NSEG (TT/KSEG)  /* 4 */
#define KVB 64

__device__ __forceinline__ u16 f2bf(float f) {
    union { float f; unsigned u; } v; v.f = f;
    unsigned r = v.u + 0x7FFFu + ((v.u >> 16) & 1u);
    return (u16)(r >> 16);
}
__device__ __forceinline__ float bf2f(u16 u) {
    union { unsigned u; float f; } v; v.u = ((unsigned)u) << 16;
    return v.f;
}
// 2^x via the trans pipe directly
__device__ __forceinline__ float fexp2(float x) {
    float r;
    asm("v_exp_f32 %0, %1" : "=v"(r) : "v"(x));
    return r;
}
// pack two f32 -> u32 of 2 bf16 (lo = a, hi = b), RTNE
__device__ __forceinline__ unsigned cvtpk(float a, float b) {
    unsigned r;
    asm("v_cvt_pk_bf16_f32 %0, %1, %2" : "=v"(r) : "v"(a), "v"(b));
    return r;
}
// async global->LDS, 16B per lane; lds base must be wave-uniform
__device__ __forceinline__ void gld_lds16(const u16* g, u16* l) {
    __builtin_amdgcn_global_load_lds(
        (const __attribute__((address_space(1))) unsigned int*)(const void*)g,
        (__attribute__((address_space(3))) unsigned int*)(void*)l,
        16, 0, 0);
}

// ---------------------------------------------------------------- x: transpose (f32) + straight cast (bf16)
__global__ __launch_bounds__(256) void transpose_x_kernel(
    const float* __restrict__ x, float* __restrict__ xt, u16* __restrict__ xb) {
    __shared__ float tile[32][33];
    int t0 = blockIdx.x * 32, e0 = blockIdx.y * 32, b = blockIdx.z;
    int tx = threadIdx.x & 31, ty = threadIdx.x >> 5;
#pragma unroll
    for (int i = 0; i < 4; i++) {
        size_t idx = ((size_t)b * TT + t0 + ty + 8 * i) * EE + e0 + tx;
        float v = x[idx];
        tile[ty + 8 * i][tx] = v;
        xb[idx] = f2bf(v);
    }
    __syncthreads();
#pragma unroll
    for (int i = 0; i < 4; i++)
        xt[((size_t)b * EE + e0 + ty + 8 * i) * TT + t0 + tx] = tile[tx][ty + 8 * i];
}

// 4 weight transposes in one launch: z=0..2 -> wqkvt slabs, z=3 -> wot
__global__ __launch_bounds__(256) void transpose_w_kernel(
    const float* __restrict__ wq, const float* __restrict__ wk,
    const float* __restrict__ wv, const float* __restrict__ wo,
    u16* __restrict__ wqkvt, u16* __restrict__ wot) {
    __shared__ float tile[32][33];
    int z = blockIdx.z;
    const float* src = (z == 0) ? wq : (z == 1) ? wk : (z == 2) ? wv : wo;
    u16* dst = (z < 3) ? (wqkvt + (size_t)z * EE * EE) : wot;
    int n0 = blockIdx.x * 32, k0 = blockIdx.y * 32;
    int tx = threadIdx.x & 31, ty = threadIdx.x >> 5;
#pragma unroll
    for (int i = 0; i < 4; i++)
        tile[ty + 8 * i][tx] = src[(size_t)(k0 + ty + 8 * i) * EE + n0 + tx];
    __syncthreads();
#pragma unroll
    for (int i = 0; i < 4; i++)
        dst[(size_t)(n0 + ty + 8 * i) * EE + k0 + tx] = f2bf(tile[tx][ty + 8 * i]);
}

// ---------------------------------------------------------------- QKV GEMM (m97 structure)
// Also writes vt[bh][d][t] directly from the V epilogue (4 consecutive t per lane).
__global__ __launch_bounds__(256) void gemm_qkv_kernel(
    const u16* __restrict__ A, const u16* __restrict__ Bt,
    u16* __restrict__ qb, u16* __restrict__ kb, u16* __restrict__ vb,
    u16* __restrict__ vt)
{
    __shared__ __align__(16) u16 As[128 * 32];
    __shared__ __align__(16) u16 Bs[128 * 32];
    const int K = EE;
    int tid = threadIdx.x;
    int w = tid >> 6, l = tid & 63;
    int lo = l & 15, hi = l >> 4;
    int wm = w >> 1, wn = w & 1;
    int m0 = blockIdx.x * 128;
    int n0 = blockIdx.y * 128;
    int srow = l >> 2, sgrp = l & 3;

    f32x4 acc[4][4] = {};
    for (int k0 = 0; k0 < K; k0 += 32) {
        __syncthreads();
        gld_lds16(A + (size_t)(m0 + w * 16 + srow) * K + k0 + sgrp * 8,       As + w * 512);
        gld_lds16(A + (size_t)(m0 + (w + 4) * 16 + srow) * K + k0 + sgrp * 8, As + (w + 4) * 512);
        gld_lds16(Bt + (size_t)(n0 + w * 16 + srow) * K + k0 + sgrp * 8,       Bs + w * 512);
        gld_lds16(Bt + (size_t)(n0 + (w + 4) * 16 + srow) * K + k0 + sgrp * 8, Bs + (w + 4) * 512);
        __syncthreads();
        bf16x8 af[4], bfr[4];
#pragma unroll
        for (int i = 0; i < 4; i++)
            af[i] = *(const bf16x8*)(As + (wm * 64 + i * 16 + lo) * 32 + hi * 8);
#pragma unroll
        for (int j = 0; j < 4; j++)
            bfr[j] = *(const bf16x8*)(Bs + (wn * 64 + j * 16 + lo) * 32 + hi * 8);
#pragma unroll
        for (int i = 0; i < 4; i++)
#pragma unroll
            for (int j = 0; j < 4; j++)
                acc[i][j] = __builtin_amdgcn_mfma_f32_16x16x32_bf16(af[i], bfr[j], acc[i][j], 0, 0, 0);
    }
    int sel = n0 / EE;
    int rem0 = n0 - sel * EE;
    u16* dst = (sel == 0) ? qb : (sel == 1) ? kb : vb;
    // q pre-scaled by 1/sqrt(D) * log2(e) so flash can use exp2 directly
    float mul = (sel == 0) ? 0.125f * 1.44269504f : 1.f;
#pragma unroll
    for (int j = 0; j < 4; j++) {
        int h = (rem0 + wn * 64 + j * 16) >> 6;
        int d = (wn * 64 + j * 16 + lo) & 63;
#pragma unroll
        for (int i = 0; i < 4; i++) {
            u16x4 pk4;
#pragma unroll
            for (int r = 0; r < 4; r++) {
                int m = m0 + wm * 64 + i * 16 + hi * 4 + r;
                int b = m >> 11, t = m & 2047;
                u16 val = f2bf(acc[i][j][r] * mul);
                pk4[r] = val;
                dst[((size_t)(b * HH + h) * TT + t) * DD + d] = val;
            }
            if (sel == 2) {
                int mbase = m0 + wm * 64 + i * 16 + hi * 4;
                int b = mbase >> 11, t = mbase & 2047;
                *(u16x4*)(vt + ((size_t)(b * HH + h) * DD + d) * TT + t) = pk4;
            }
        }
    }
}

// ---------------------------------------------------------------- r = scale * x . wr
__global__ __launch_bounds__(256) void r_partial_kernel(
    const float* __restrict__ xt, const float* __restrict__ wr, float* __restrict__ rp) {
    int ech = blockIdx.x;           // 0..47
    int tch = blockIdx.y;           // 0..1
    int hg = blockIdx.z;            // 0..1
    int e0 = ech * 16, h0 = hg * 6;
    int tv = tch * 256 + threadIdx.x;
    const f32x4* xt4 = (const f32x4*)xt;
    const f32x4* wr4 = (const f32x4*)wr;
    f32x4 acc[2][6] = {};
#pragma unroll 4
    for (int e = 0; e < 16; e++) {
        f32x4 x0 = xt4[(size_t)(e0 + e) * 512 + tv];
        f32x4 x1 = xt4[(size_t)(EE + e0 + e) * 512 + tv];
#pragma unroll
        for (int hh = 0; hh < 6; hh++) {
            f32x4 w = wr4[((size_t)(h0 + hh) * EE + e0 + e) * 512 + tv];
            acc[0][hh] += w * x0;
            acc[1][hh] += w * x1;
        }
    }
    f32x4* rp4 = (f32x4*)rp;
#pragma unroll
    for (int b = 0; b < 2; b++)
#pragma unroll
        for (int hh = 0; hh < 6; hh++)
            rp4[((size_t)ech * 24 + b * 12 + h0 + hh) * 512 + tv] = acc[b][hh];
}

__global__ __launch_bounds__(256) void r_reduce_kernel(
    const float* __restrict__ rp, float* __restrict__ r, float* __restrict__ rmax) {
    int bh = blockIdx.x, tid = threadIdx.x;
    const f32x4* rp4 = (const f32x4*)rp;
    f32x4* r4 = (f32x4*)r;
    float mloc = -INFINITY;
#pragma unroll
    for (int seg = 0; seg < 2; seg++) {
        int tv = seg * 256 + tid;
        f32x4 s = {};
#pragma unroll 8
        for (int ech = 0; ech < 48; ech++)
            s += rp4[((size_t)ech * 24 + bh) * 512 + tv];
        s *= 0.125f;
        r4[(size_t)bh * 512 + tv] = s;
        mloc = fmaxf(mloc, fmaxf(fmaxf(s[0], s[1]), fmaxf(s[2], s[3])));
    }
    __shared__ float sm[256];
    sm[tid] = mloc; __syncthreads();
    for (int s = 128; s > 0; s >>= 1) {
        if (tid < s) sm[tid] = fmaxf(sm[tid], sm[tid + s]);
        __syncthreads();
    }
    if (tid == 0) rmax[bh] = sm[0];
}

// ---------------------------------------------------------------- rr attention = chunked prefix scan
__global__ __launch_bounds__(64) void scan_part_kernel(
    const float* __restrict__ r, const float* __restrict__ rmax,
    const u16* __restrict__ vb, float* __restrict__ Sv, float* __restrict__ Sl) {
    int c = blockIdx.x, bh = blockIdx.y, d = threadIdx.x;
    float mx = rmax[bh];
    const float* rp = r + (size_t)bh * TT + c * 128;
    const u16* vp = vb + ((size_t)bh * TT + c * 128) * DD + d;
    float accv = 0.f, accl = 0.f;
#pragma unroll 4
    for (int j = 0; j < 128; j++) {
        float w = __expf(rp[j] - mx);
        accv += w * bf2f(vp[(size_t)j * DD]);
        accl += w;
    }
    Sv[((size_t)bh * SCH + c) * DD + d] = accv;
    if (d == 0) Sl[bh * SCH + c] = accl;
}

__global__ __launch_bounds__(64) void scan_out_kernel(
    const float* __restrict__ r, const float* __restrict__ rmax,
    const u16* __restrict__ vb, const float* __restrict__ Sv, const float* __restrict__ Sl,
    u16* __restrict__ outr) {
    int c = blockIdx.x, bh = blockIdx.y, d = threadIdx.x;
    float mx = rmax[bh];
    float acc = 0.f, accl = 0.f;
    for (int cp = 0; cp < c; cp++) {
        acc += Sv[((size_t)bh * SCH + cp) * DD + d];
        accl += Sl[bh * SCH + cp];
    }
    const float* rp = r + (size_t)bh * TT + c * 128;
    const u16* vp = vb + ((size_t)bh * TT + c * 128) * DD + d;
    u16* op = outr + ((size_t)bh * TT + c * 128) * DD + d;
#pragma unroll 2
    for (int j = 0; j < 128; j++) {
        float w = __expf(rp[j] - mx);
        acc += w * bf2f(vp[(size_t)j * DD]);
        accl += w;
        op[(size_t)j * DD] = f2bf(acc * __builtin_amdgcn_rcpf(accl));
    }
}

// ---------------------------------------------------------------- content flash attention
// 1 wave / 32 q-rows, barrier-free, NO LDS. K/V fragments held in persistent
// registers (kR[8], vR[8]) with staggered single-buffer prefetch:
//   QK^T consumes kR -> issue loadK(next) -> softmax (hides K latency)
//   -> PV consumes vR -> issue loadV(next) (hidden under next QK+softmax).
// grid.x = bh for XCD L2 locality (3 bh/XCD, K+V 1.5 MB L2-resident).
// S^T = mfma32(K, Q): lane owns q = q0 + (l&31). Softmax in-register, defer-max.
// P^T B-frags via cvt_pk + permlane32_swap. PV: O^T = mfma32(V^T, P^T).
__global__ __launch_bounds__(64, 2) void flash_kernel(
    const u16* __restrict__ qb, const u16* __restrict__ kb,
    const u16* __restrict__ vt, u16* __restrict__ op,
    float* __restrict__ mb, float* __restrict__ lb) {
    int bh = blockIdx.x;
    int ti = (int)gridDim.y - 1 - (int)blockIdx.y;   // heavy tiles first
    int sg = blockIdx.z;
    int q0 = ti * 32;
    int ks0 = sg * KSEG;
    if (ks0 > q0) return;                   // segment has no causal keys for this tile
    int kend = min(ks0 + KSEG, q0 + 32);
    int nc = (kend - ks0 + 63) >> 6;
    int l = threadIdx.x;
    int q31 = l & 31, hb = l >> 5;
    int myq = q0 + q31;
    const u16* qbase = qb + (size_t)bh * TT * DD;
    const u16* kbase = kb + (size_t)bh * TT * DD;
    const u16* vtb = vt + (size_t)bh * DD * TT;

    // Q B-frags: col=q, k(d) = mm*16 + hb*8 + e
    bf16x8 bQ[4];
#pragma unroll
    for (int mm = 0; mm < 4; mm++)
        bQ[mm] = *(const bf16x8*)(qbase + (size_t)myq * DD + mm * 16 + hb * 8);

    bf16x8 kR[8], vR[8];
    auto loadK = [&](int j0) {
#pragma unroll
        for (int kt = 0; kt < 2; kt++)
#pragma unroll
            for (int mm = 0; mm < 4; mm++)
                kR[kt * 4 + mm] = *(const bf16x8*)(kbase + (size_t)(j0 + kt * 32 + q31) * DD + mm * 16 + hb * 8);
    };
    auto loadV = [&](int j0) {
#pragma unroll
        for (int kt = 0; kt < 2; kt++)
#pragma unroll
            for (int f2 = 0; f2 < 2; f2++)
#pragma unroll
                for (int dt = 0; dt < 2; dt++)
                    vR[(kt * 2 + f2) * 2 + dt] =
                        *(const bf16x8*)(vtb + (size_t)(dt * 32 + q31) * TT + j0 + (kt * 4 + f2 * 2 + hb) * 8);
    };

    float m_ = -INFINITY, ls = 0.f;
    f32x16 o[2] = {};

    loadK(ks0);
    loadV(ks0);
    for (int ci = 0; ci < nc; ci++) {
        int j0 = ks0 + ci * 64;
        bool more = (ci + 1 < nc);
        // S^T: s[kt][reg] = score(q=myq, k = j0 + kt*32 + (reg&3)+8*(reg>>2)+4*hb)
        f32x16 s[2] = {};
#pragma unroll
        for (int kt = 0; kt < 2; kt++)
#pragma unroll
            for (int mm = 0; mm < 4; mm++)
                s[kt] = __builtin_amdgcn_mfma_f32_32x32x16_bf16(kR[kt * 4 + mm], bQ[mm], s[kt], 0, 0, 0);
        if (more) loadK(j0 + 64);            // K latency hides under softmax below
        if (j0 + 63 > q0) {
#pragma unroll
            for (int kt = 0; kt < 2; kt++)
#pragma unroll
                for (int reg = 0; reg < 16; reg++) {
                    int k = j0 + kt * 32 + (reg & 3) + 8 * (reg >> 2) + 4 * hb;
                    if (k > myq) s[kt][reg] = -INFINITY;
                }
        }
        float tm = -INFINITY;
#pragma unroll
        for (int kt = 0; kt < 2; kt++)
#pragma unroll
            for (int reg = 0; reg < 16; reg++) tm = fmaxf(tm, s[kt][reg]);
        tm = fmaxf(tm, __shfl_xor(tm, 32, 64));
        // defer-max: only rescale when the new tile max meaningfully exceeds m_
        if (__any(tm > m_ + 8.f)) {
            float mn = fmaxf(m_, tm);
            float f = fexp2(m_ - mn);
            m_ = mn;
            ls *= f;
#pragma unroll
            for (int dt = 0; dt < 2; dt++)
#pragma unroll
                for (int reg = 0; reg < 16; reg++) o[dt][reg] *= f;
        }
        float rs = 0.f;
#pragma unroll
        for (int kt = 0; kt < 2; kt++)
#pragma unroll
            for (int reg = 0; reg < 16; reg++) {
                s[kt][reg] = fexp2(s[kt][reg] - m_);
                rs += s[kt][reg];
            }
        rs += __shfl_xor(rs, 32, 64);
        ls += rs;

        // P^T B-frags + PV (consumes vR)
#pragma unroll
        for (int kt = 0; kt < 2; kt++) {
            unsigned W[4][2];
#pragma unroll
            for (int g4 = 0; g4 < 4; g4++) {
                W[g4][0] = cvtpk(s[kt][4 * g4], s[kt][4 * g4 + 1]);
                W[g4][1] = cvtpk(s[kt][4 * g4 + 2], s[kt][4 * g4 + 3]);
            }
#pragma unroll
            for (int f2 = 0; f2 < 2; f2++) {
                unsigned a0 = W[2 * f2][0], b0 = W[2 * f2 + 1][0];
                unsigned a1 = W[2 * f2][1], b1 = W[2 * f2 + 1][1];
                asm volatile("v_permlane32_swap_b32 %0, %1" : "+v"(a0), "+v"(b0));
                asm volatile("v_permlane32_swap_b32 %0, %1" : "+v"(a1), "+v"(b1));
                union { unsigned u[4]; bf16x8 v; } bp;
                bp.u[0] = a0; bp.u[1] = a1; bp.u[2] = b0; bp.u[3] = b1;
#pragma unroll
                for (int dt = 0; dt < 2; dt++)
                    o[dt] = __builtin_amdgcn_mfma_f32_32x32x16_bf16(vR[(kt * 2 + f2) * 2 + dt], bp.v, o[dt], 0, 0, 0);
            }
        }
        if (more) loadV(j0 + 64);            // V latency hides under next QK^T+softmax
    }
    size_t pb = (size_t)(bh * NSEG + sg) * TT;
    float inv = 1.f / ls;
#pragma unroll
    for (int dt = 0; dt < 2; dt++)
#pragma unroll
        for (int g4 = 0; g4 < 4; g4++) {
            u16x4 pk4;
#pragma unroll
            for (int c = 0; c < 4; c++) pk4[c] = f2bf(o[dt][4 * g4 + c] * inv);
            *(u16x4*)(op + (pb + myq) * DD + dt * 32 + 8 * g4 + 4 * hb) = pk4;
        }
    if (hb == 0) {
        mb[pb + myq] = m_;
        lb[pb + myq] = ls;
    }
}

// merge partials (weights computed inline, base-2 domain) + combine with rr branch
__global__ void merge_kernel(const u16* __restrict__ op,
                             const float* __restrict__ mb, const float* __restrict__ lb,
                             const u16* __restrict__ outr, const float* __restrict__ alpha,
                             u16* __restrict__ comb) {
    int i8 = blockIdx.x * blockDim.x + threadIdx.x;
    if (i8 >= M4 * EE / 8) return;
    int bt = i8 / (EE / 8), c8 = i8 - bt * (EE / 8);
    int h = c8 >> 3, d8 = c8 & 7;
    int b = bt >> 11, t = bt & 2047;
    int bh = b * HH + h;
    int ns = (t >> 9) + 1;
    size_t base = (size_t)bh * NSEG * TT + t;
    float M = -INFINITY;
    for (int s = 0; s < ns; s++) M = fmaxf(M, mb[base + (size_t)s * TT]);
    float e[NSEG], L = 0.f;
    for (int s = 0; s < ns; s++) {
        e[s] = lb[base + (size_t)s * TT] * fexp2(mb[base + (size_t)s * TT] - M);
        L += e[s];
    }
    float invL = 1.f / L;
    float acc[8] = {};
    for (int s = 0; s < ns; s++) {
        size_t row = base + (size_t)s * TT;
        float wv = e[s] * invL;
        union { u16 u[8]; bf16x8 v; } pv;
        pv.v = *(const bf16x8*)(op + row * DD + d8 * 8);
#pragma unroll
        for (int ee = 0; ee < 8; ee++) acc[ee] += wv * bf2f(pv.u[ee]);
    }
    float a = 1.f / (1.f + __expf(-alpha[h]));
    union { u16 u[8]; bf16x8 v; } vr, vo;
    vr.v = *(const bf16x8*)(outr + (((size_t)bh * TT + t) * DD + d8 * 8));
#pragma unroll
    for (int ee = 0; ee < 8; ee++)
        vo.u[ee] = f2bf(a * bf2f(vr.u[ee]) + (1.f - a) * acc[ee]);
    ((bf16x8*)comb)[i8] = vo.v;
}

// ---------------------------------------------------------------- output GEMM (m97 structure)
__global__ __launch_bounds__(256) void gemm_out_kernel(const u16* __restrict__ A,
                                                       const u16* __restrict__ Bt,
                                                       float* __restrict__ C) {
    __shared__ __align__(16) u16 As[128 * 32];
    __shared__ __align__(16) u16 Bs[128 * 32];
    const int K = EE;
    int tid = threadIdx.x;
    int w = tid >> 6, l = tid & 63;
    int lo = l & 15, hi = l >> 4;
    int wm = w >> 1, wn = w & 1;
    int m0 = blockIdx.x * 128;
    int n0 = blockIdx.y * 128;
    int srow = l >> 2, sgrp = l & 3;

    f32x4 acc[4][4] = {};
    for (int k0 = 0; k0 < K; k0 += 32) {
        __syncthreads();
        gld_lds16(A + (size_t)(m0 + w * 16 + srow) * K + k0 + sgrp * 8,       As + w * 512);
        gld_lds16(A + (size_t)(m0 + (w + 4) * 16 + srow) * K + k0 + sgrp * 8, As + (w + 4) * 512);
        gld_lds16(Bt + (size_t)(n0 + w * 16 + srow) * K + k0 + sgrp * 8,       Bs + w * 512);
        gld_lds16(Bt + (size_t)(n0 + (w + 4) * 16 + srow) * K + k0 + sgrp * 8, Bs + (w + 4) * 512);
        __syncthreads();
        bf16x8 af[4], bfr[4];
#pragma unroll
        for (int i = 0; i < 4; i++)
            af[i] = *(const bf16x8*)(As + (wm * 64 + i * 16 + lo) * 32 + hi * 8);
#pragma unroll
        for (int j = 0; j < 4; j++)
            bfr[j] = *(const bf16x8*)(Bs + (wn * 64 + j * 16 + lo) * 32 + hi * 8);
#pragma unroll
        for (int i = 0; i < 4; i++)
#pragma unroll
            for (int j = 0; j < 4; j++)
                acc[i][j] = __builtin_amdgcn_mfma_f32_16x16x32_bf16(af[i], bfr[j], acc[i][j], 0, 0, 0);
    }
#pragma unroll
    for (int i = 0; i < 4; i++)
#pragma unroll
        for (int j = 0; j < 4; j++)
#pragma unroll
            for (int r = 0; r < 4; r++) {
                int m = m0 + wm * 64 + i * 16 + hi * 4 + r;
                int n = n0 + wn * 64 + j * 16 + lo;
                C[(size_t)m * EE + n] = acc[i][j][r];
            }
}

// ----------------------------------------------------------------
extern "C" void kernel_launch(void* const* d_in, const int* in_sizes, int n_in,
                              void* d_out, int out_size, void* d_ws, size_t ws_size,
                              hipStream_t stream) {
    const float* x = (const float*)d_in[0];
    const float* wq = (const float*)d_in[1];
    const float* wk = (const float*)d_in[2];
    const float* wv = (const float*)d_in[3];
    const float* wr = (const float*)d_in[4];
    const float* alpha = (const float*)d_in[5];
    const float* wo = (const float*)d_in[6];
    float* out = (float*)d_out;

    char* ws = (char*)d_ws;
    size_t off = 0;
    auto carve = [&](size_t bytes) -> char* {
        char* p = ws + off;
        off += (bytes + 255) & ~(size_t)255;
        return p;
    };
    u16* xb    = (u16*)carve((size_t)M4 * EE * 2);
    u16* wqkvt = (u16*)carve((size_t)NQKV * EE * 2);
    u16* wot   = (u16*)carve((size_t)EE * EE * 2);
    u16* qb    = (u16*)carve((size_t)BH * TT * DD * 2);
    u16* kb    = (u16*)carve((size_t)BH * TT * DD * 2);
    u16* vb    = (u16*)carve((size_t)BH * TT * DD * 2);
    u16* vt    = (u16*)carve((size_t)BH * TT * DD * 2);
    float* xt   = (float*)carve((size_t)BB * EE * TT * 4);
    float* rpbuf= (float*)carve((size_t)48 * BH * TT * 4);
    float* rbuf = (float*)carve((size_t)BH * TT * 4);
    float* rmx  = (float*)carve((size_t)BH * 4);
    float* Sv   = (float*)carve((size_t)BH * SCH * DD * 4);
    float* Sl   = (float*)carve((size_t)BH * SCH * 4);
    u16* outr  = (u16*)carve((size_t)BH * TT * DD * 2);
    u16* opart = (u16*)carve((size_t)BH * NSEG * TT * DD * 2);
    float* mbuf = (float*)carve((size_t)BH * NSEG * TT * 4);
    float* lbuf = (float*)carve((size_t)BH * NSEG * TT * 4);
    u16* comb  = (u16*)carve((size_t)M4 * EE * 2);

    transpose_x_kernel<<<dim3(TT / 32, EE / 32, BB), 256, 0, stream>>>(x, xt, xb);
    transpose_w_kernel<<<dim3(EE / 32, EE / 32, 4), 256, 0, stream>>>(wq, wk, wv, wo, wqkvt, wot);

    dim3 gq(M4 / 128, NQKV / 128);
    gemm_qkv_kernel<<<gq, 256, 0, stream>>>(xb, wqkvt, qb, kb, vb, vt);

    r_partial_kernel<<<dim3(48, 2, 2), 256, 0, stream>>>(xt, wr, rpbuf);
    r_reduce_kernel<<<BH, 256, 0, stream>>>(rpbuf, rbuf, rmx);

    scan_part_kernel<<<dim3(SCH, BH), 64, 0, stream>>>(rbuf, rmx, vb, Sv, Sl);
    scan_out_kernel<<<dim3(SCH, BH), 64, 0, stream>>>(rbuf, rmx, vb, Sv, Sl, outr);

    flash_kernel<<<dim3(BH, TT / 32, NSEG), 64, 0, stream>>>(qb, kb, vt, opart, mbuf, lbuf);
    merge_kernel<<<(M4 * EE / 8 + 255) / 256, 256, 0, stream>>>(opart, mbuf, lbuf, outr, alpha, comb);

    dim3 go(M4 / 128, EE / 128);
    gemm_out_kernel<<<go, 256, 0, stream>>>(comb, wot, out);
}

// Round 12
// 160.300 us; speedup vs baseline: 1.1056x; 1.1056x over previous
//
#include <hip/hip_runtime.h>
#include <math.h>

typedef __bf16 bf16x8 __attribute__((ext_vector_type(8)));
typedef float f32x4 __attribute__((ext_vector_type(4)));
typedef float f32x16 __attribute__((ext_vector_type(16)));
typedef unsigned short u16;
typedef unsigned short u16x4 __attribute__((ext_vector_type(4)));

#define BB 2
#define TT 2048
#define EE 768
#define HH 12
#define DD 64
#define BH (BB*HH)      /* 24 */
#define M4 (BB*TT)      /* 4096 */
#define NQKV (3*EE)     /* 2304 */
#define SCH 16          /* scan chunks (128 t each) */
#define KSEG 512        /* flash split-K segment */
#define NSEG (TT/KSEG)  /* 4 */
#define KVB 64
#define QBLK 128

__device__ __forceinline__ u16 f2bf(float f) {
    union { float f; unsigned u; } v; v.f = f;
    unsigned r = v.u + 0x7FFFu + ((v.u >> 16) & 1u);
    return (u16)(r >> 16);
}
__device__ __forceinline__ float bf2f(u16 u) {
    union { unsigned u; float f; } v; v.u = ((unsigned)u) << 16;
    return v.f;
}
// 2^x via the trans pipe directly
__device__ __forceinline__ float fexp2(float x) {
    float r;
    asm("v_exp_f32 %0, %1" : "=v"(r) : "v"(x));
    return r;
}
// pack two f32 -> u32 of 2 bf16 (lo = a, hi = b), RTNE
__device__ __forceinline__ unsigned cvtpk(float a, float b) {
    unsigned r;
    asm("v_cvt_pk_bf16_f32 %0, %1, %2" : "=v"(r) : "v"(a), "v"(b));
    return r;
}
// u16 index of 8-elem group `grp` in row `row` of a [*,64] u16 LDS tile, XOR-swizzled
__device__ __forceinline__ int swz(int row, int grp) {
    return row * 64 + ((grp ^ (row & 7)) << 3);
}
// async global->LDS, 16B per lane; lds base must be wave-uniform
__device__ __forceinline__ void gld_lds16(const u16* g, u16* l) {
    __builtin_amdgcn_global_load_lds(
        (const __attribute__((address_space(1))) unsigned int*)(const void*)g,
        (__attribute__((address_space(3))) unsigned int*)(void*)l,
        16, 0, 0);
}

// ---------------------------------------------------------------- x: transpose (f32) + straight cast (bf16)
__global__ __launch_bounds__(256) void transpose_x_kernel(
    const float* __restrict__ x, float* __restrict__ xt, u16* __restrict__ xb) {
    __shared__ float tile[32][33];
    int t0 = blockIdx.x * 32, e0 = blockIdx.y * 32, b = blockIdx.z;
    int tx = threadIdx.x & 31, ty = threadIdx.x >> 5;
#pragma unroll
    for (int i = 0; i < 4; i++) {
        size_t idx = ((size_t)b * TT + t0 + ty + 8 * i) * EE + e0 + tx;
        float v = x[idx];
        tile[ty + 8 * i][tx] = v;
        xb[idx] = f2bf(v);
    }
    __syncthreads();
#pragma unroll
    for (int i = 0; i < 4; i++)
        xt[((size_t)b * EE + e0 + ty + 8 * i) * TT + t0 + tx] = tile[tx][ty + 8 * i];
}

// 4 weight transposes in one launch: z=0..2 -> wqkvt slabs, z=3 -> wot
__global__ __launch_bounds__(256) void transpose_w_kernel(
    const float* __restrict__ wq, const float* __restrict__ wk,
    const float* __restrict__ wv, const float* __restrict__ wo,
    u16* __restrict__ wqkvt, u16* __restrict__ wot) {
    __shared__ float tile[32][33];
    int z = blockIdx.z;
    const float* src = (z == 0) ? wq : (z == 1) ? wk : (z == 2) ? wv : wo;
    u16* dst = (z < 3) ? (wqkvt + (size_t)z * EE * EE) : wot;
    int n0 = blockIdx.x * 32, k0 = blockIdx.y * 32;
    int tx = threadIdx.x & 31, ty = threadIdx.x >> 5;
#pragma unroll
    for (int i = 0; i < 4; i++)
        tile[ty + 8 * i][tx] = src[(size_t)(k0 + ty + 8 * i) * EE + n0 + tx];
    __syncthreads();
#pragma unroll
    for (int i = 0; i < 4; i++)
        dst[(size_t)(n0 + ty + 8 * i) * EE + k0 + tx] = f2bf(tile[tx][ty + 8 * i]);
}

// ---------------------------------------------------------------- QKV GEMM (m97 structure)
// Also writes vt[bh][d][t] directly from the V epilogue (4 consecutive t per lane).
__global__ __launch_bounds__(256) void gemm_qkv_kernel(
    const u16* __restrict__ A, const u16* __restrict__ Bt,
    u16* __restrict__ qb, u16* __restrict__ kb, u16* __restrict__ vb,
    u16* __restrict__ vt)
{
    __shared__ __align__(16) u16 As[128 * 32];
    __shared__ __align__(16) u16 Bs[128 * 32];
    const int K = EE;
    int tid = threadIdx.x;
    int w = tid >> 6, l = tid & 63;
    int lo = l & 15, hi = l >> 4;
    int wm = w >> 1, wn = w & 1;
    int m0 = blockIdx.x * 128;
    int n0 = blockIdx.y * 128;
    int srow = l >> 2, sgrp = l & 3;

    f32x4 acc[4][4] = {};
    for (int k0 = 0; k0 < K; k0 += 32) {
        __syncthreads();
        gld_lds16(A + (size_t)(m0 + w * 16 + srow) * K + k0 + sgrp * 8,       As + w * 512);
        gld_lds16(A + (size_t)(m0 + (w + 4) * 16 + srow) * K + k0 + sgrp * 8, As + (w + 4) * 512);
        gld_lds16(Bt + (size_t)(n0 + w * 16 + srow) * K + k0 + sgrp * 8,       Bs + w * 512);
        gld_lds16(Bt + (size_t)(n0 + (w + 4) * 16 + srow) * K + k0 + sgrp * 8, Bs + (w + 4) * 512);
        __syncthreads();
        bf16x8 af[4], bfr[4];
#pragma unroll
        for (int i = 0; i < 4; i++)
            af[i] = *(const bf16x8*)(As + (wm * 64 + i * 16 + lo) * 32 + hi * 8);
#pragma unroll
        for (int j = 0; j < 4; j++)
            bfr[j] = *(const bf16x8*)(Bs + (wn * 64 + j * 16 + lo) * 32 + hi * 8);
#pragma unroll
        for (int i = 0; i < 4; i++)
#pragma unroll
            for (int j = 0; j < 4; j++)
                acc[i][j] = __builtin_amdgcn_mfma_f32_16x16x32_bf16(af[i], bfr[j], acc[i][j], 0, 0, 0);
    }
    int sel = n0 / EE;
    int rem0 = n0 - sel * EE;
    u16* dst = (sel == 0) ? qb : (sel == 1) ? kb : vb;
    // q pre-scaled by 1/sqrt(D) * log2(e) so flash can use exp2 directly
    float mul = (sel == 0) ? 0.125f * 1.44269504f : 1.f;
#pragma unroll
    for (int j = 0; j < 4; j++) {
        int h = (rem0 + wn * 64 + j * 16) >> 6;
        int d = (wn * 64 + j * 16 + lo) & 63;
#pragma unroll
        for (int i = 0; i < 4; i++) {
            u16x4 pk4;
#pragma unroll
            for (int r = 0; r < 4; r++) {
                int m = m0 + wm * 64 + i * 16 + hi * 4 + r;
                int b = m >> 11, t = m & 2047;
                u16 val = f2bf(acc[i][j][r] * mul);
                pk4[r] = val;
                dst[((size_t)(b * HH + h) * TT + t) * DD + d] = val;
            }
            if (sel == 2) {
                int mbase = m0 + wm * 64 + i * 16 + hi * 4;
                int b = mbase >> 11, t = mbase & 2047;
                *(u16x4*)(vt + ((size_t)(b * HH + h) * DD + d) * TT + t) = pk4;
            }
        }
    }
}

// ---------------------------------------------------------------- r = scale * x . wr
__global__ __launch_bounds__(256) void r_partial_kernel(
    const float* __restrict__ xt, const float* __restrict__ wr, float* __restrict__ rp) {
    int ech = blockIdx.x;           // 0..47
    int tch = blockIdx.y;           // 0..1
    int hg = blockIdx.z;            // 0..1
    int e0 = ech * 16, h0 = hg * 6;
    int tv = tch * 256 + threadIdx.x;
    const f32x4* xt4 = (const f32x4*)xt;
    const f32x4* wr4 = (const f32x4*)wr;
    f32x4 acc[2][6] = {};
#pragma unroll 4
    for (int e = 0; e < 16; e++) {
        f32x4 x0 = xt4[(size_t)(e0 + e) * 512 + tv];
        f32x4 x1 = xt4[(size_t)(EE + e0 + e) * 512 + tv];
#pragma unroll
        for (int hh = 0; hh < 6; hh++) {
            f32x4 w = wr4[((size_t)(h0 + hh) * EE + e0 + e) * 512 + tv];
            acc[0][hh] += w * x0;
            acc[1][hh] += w * x1;
        }
    }
    f32x4* rp4 = (f32x4*)rp;
#pragma unroll
    for (int b = 0; b < 2; b++)
#pragma unroll
        for (int hh = 0; hh < 6; hh++)
            rp4[((size_t)ech * 24 + b * 12 + h0 + hh) * 512 + tv] = acc[b][hh];
}

__global__ __launch_bounds__(256) void r_reduce_kernel(
    const float* __restrict__ rp, float* __restrict__ r, float* __restrict__ rmax) {
    int bh = blockIdx.x, tid = threadIdx.x;
    const f32x4* rp4 = (const f32x4*)rp;
    f32x4* r4 = (f32x4*)r;
    float mloc = -INFINITY;
#pragma unroll
    for (int seg = 0; seg < 2; seg++) {
        int tv = seg * 256 + tid;
        f32x4 s = {};
#pragma unroll 8
        for (int ech = 0; ech < 48; ech++)
            s += rp4[((size_t)ech * 24 + bh) * 512 + tv];
        s *= 0.125f;
        r4[(size_t)bh * 512 + tv] = s;
        mloc = fmaxf(mloc, fmaxf(fmaxf(s[0], s[1]), fmaxf(s[2], s[3])));
    }
    __shared__ float sm[256];
    sm[tid] = mloc; __syncthreads();
    for (int s = 128; s > 0; s >>= 1) {
        if (tid < s) sm[tid] = fmaxf(sm[tid], sm[tid + s]);
        __syncthreads();
    }
    if (tid == 0) rmax[bh] = sm[0];
}

// ---------------------------------------------------------------- rr attention = chunked prefix scan
__global__ __launch_bounds__(64) void scan_part_kernel(
    const float* __restrict__ r, const float* __restrict__ rmax,
    const u16* __restrict__ vb, float* __restrict__ Sv, float* __restrict__ Sl) {
    int c = blockIdx.x, bh = blockIdx.y, d = threadIdx.x;
    float mx = rmax[bh];
    const float* rp = r + (size_t)bh * TT + c * 128;
    const u16* vp = vb + ((size_t)bh * TT + c * 128) * DD + d;
    float accv = 0.f, accl = 0.f;
#pragma unroll 4
    for (int j = 0; j < 128; j++) {
        float w = __expf(rp[j] - mx);
        accv += w * bf2f(vp[(size_t)j * DD]);
        accl += w;
    }
    Sv[((size_t)bh * SCH + c) * DD + d] = accv;
    if (d == 0) Sl[bh * SCH + c] = accl;
}

__global__ __launch_bounds__(64) void scan_out_kernel(
    const float* __restrict__ r, const float* __restrict__ rmax,
    const u16* __restrict__ vb, const float* __restrict__ Sv, const float* __restrict__ Sl,
    u16* __restrict__ outr) {
    int c = blockIdx.x, bh = blockIdx.y, d = threadIdx.x;
    float mx = rmax[bh];
    float acc = 0.f, accl = 0.f;
    for (int cp = 0; cp < c; cp++) {
        acc += Sv[((size_t)bh * SCH + cp) * DD + d];
        accl += Sl[bh * SCH + cp];
    }
    const float* rp = r + (size_t)bh * TT + c * 128;
    const u16* vp = vb + ((size_t)bh * TT + c * 128) * DD + d;
    u16* op = outr + ((size_t)bh * TT + c * 128) * DD + d;
#pragma unroll 2
    for (int j = 0; j < 128; j++) {
        float w = __expf(rp[j] - mx);
        acc += w * bf2f(vp[(size_t)j * DD]);
        accl += w;
        op[(size_t)j * DD] = f2bf(acc * __builtin_amdgcn_rcpf(accl));
    }
}

// ---------------------------------------------------------------- content flash attention, split-K, 32x32 MFMA
// Double-buffered async K/V staging (global_load_lds, pre-swizzled global src).
// S^T = mfma32(K, Q): lane owns q = qw0 + (l&31); softmax in-register; defer-max THR=8.
// P^T B-frags via cvt_pk + permlane32_swap. PV: O^T = mfma32(V^T, P^T).
// s_setprio(1) around MFMA clusters (T5: dbuf loop has wave role-diversity).
__global__ __launch_bounds__(256) void flash_kernel(
    const u16* __restrict__ qb, const u16* __restrict__ kb,
    const u16* __restrict__ vt, u16* __restrict__ op,
    float* __restrict__ mb, float* __restrict__ lb) {
    __shared__ __align__(16) u16 KV[2][2][64 * 64];   // [buf][K/V][row*64]
    int qt = (int)gridDim.x - 1 - (int)blockIdx.x;   // heavy tiles first
    int sg = blockIdx.y, bh = blockIdx.z;
    int q0 = qt * QBLK;
    int ks0 = sg * KSEG;
    if (ks0 > q0) return;                   // segment has no causal keys for this tile
    int kend = min(ks0 + KSEG, q0 + QBLK);
    int nc = (kend - ks0) >> 6;
    int tid = threadIdx.x, w = tid >> 6, l = tid & 63;
    int q31 = l & 31, hb = l >> 5;
    int qw0 = q0 + w * 32;
    int myq = qw0 + q31;
    const u16* qbase = qb + (size_t)bh * TT * DD;
    const u16* kbase = kb + (size_t)bh * TT * DD;
    const u16* vtb = vt + (size_t)bh * DD * TT;

    // staging coords: lane -> (row, slot); global src pre-swizzled so linear LDS dest
    // matches the swz() read pattern
    int sr0 = w * 8 + (l >> 3);
    int sg8 = (((l & 7) ^ (sr0 & 7)) << 3);
    auto stage = [&](int j0, int bbuf) {
        u16* kd = &KV[bbuf][0][0];
        u16* vd = &KV[bbuf][1][0];
        gld_lds16(kbase + (size_t)(j0 + sr0) * DD + sg8,      kd + w * 512);
        gld_lds16(kbase + (size_t)(j0 + sr0 + 32) * DD + sg8, kd + 2048 + w * 512);
        gld_lds16(vtb + (size_t)sr0 * TT + j0 + sg8,          vd + w * 512);
        gld_lds16(vtb + (size_t)(sr0 + 32) * TT + j0 + sg8,   vd + 2048 + w * 512);
    };

    // Q B-frags: col=q, k(d) = mm*16 + hb*8 + e
    bf16x8 bQ[4];
#pragma unroll
    for (int mm = 0; mm < 4; mm++)
        bQ[mm] = *(const bf16x8*)(qbase + (size_t)myq * DD + mm * 16 + hb * 8);

    float m_ = -INFINITY, ls = 0.f;
    f32x16 o[2] = {};

    stage(ks0, 0);
    __syncthreads();
    for (int ci = 0; ci < nc; ci++) {
        int j0 = ks0 + ci * 64;
        int bbuf = ci & 1;
        if (ci + 1 < nc) stage(j0 + 64, bbuf ^ 1);   // async, overlaps compute below
        if (j0 <= qw0 + 31) {
            const u16* Kt = &KV[bbuf][0][0];
            const u16* Vt = &KV[bbuf][1][0];
            // S^T: s[kt][reg] = score(q=myq, k = j0 + kt*32 + (reg&3)+8*(reg>>2)+4*hb)
            f32x16 s[2] = {};
            __builtin_amdgcn_s_setprio(1);
#pragma unroll
            for (int kt = 0; kt < 2; kt++)
#pragma unroll
                for (int mm = 0; mm < 4; mm++) {
                    bf16x8 aK = *(const bf16x8*)(Kt + swz(kt * 32 + q31, mm * 2 + hb));
                    s[kt] = __builtin_amdgcn_mfma_f32_32x32x16_bf16(aK, bQ[mm], s[kt], 0, 0, 0);
                }
            __builtin_amdgcn_s_setprio(0);
            if (j0 + 63 > qw0) {
#pragma unroll
                for (int kt = 0; kt < 2; kt++)
#pragma unroll
                    for (int reg = 0; reg < 16; reg++) {
                        int k = j0 + kt * 32 + (reg & 3) + 8 * (reg >> 2) + 4 * hb;
                        if (k > myq) s[kt][reg] = -INFINITY;
                    }
            }
            float tm = -INFINITY;
#pragma unroll
            for (int kt = 0; kt < 2; kt++)
#pragma unroll
                for (int reg = 0; reg < 16; reg++) tm = fmaxf(tm, s[kt][reg]);
            tm = fmaxf(tm, __shfl_xor(tm, 32, 64));
            // defer-max: only rescale when the new tile max meaningfully exceeds m_
            if (__any(tm > m_ + 8.f)) {
                float mn = fmaxf(m_, tm);
                float f = fexp2(m_ - mn);
                m_ = mn;
                ls *= f;
#pragma unroll
                for (int dt = 0; dt < 2; dt++)
#pragma unroll
                    for (int reg = 0; reg < 16; reg++) o[dt][reg] *= f;
            }
            float rs = 0.f;
#pragma unroll
            for (int kt = 0; kt < 2; kt++)
#pragma unroll
                for (int reg = 0; reg < 16; reg++) {
                    s[kt][reg] = fexp2(s[kt][reg] - m_);
                    rs += s[kt][reg];
                }
            rs += __shfl_xor(rs, 32, 64);
            ls += rs;

            // P^T B-frags + PV
            __builtin_amdgcn_s_setprio(1);
#pragma unroll
            for (int kt = 0; kt < 2; kt++) {
                unsigned W[4][2];
#pragma unroll
                for (int g4 = 0; g4 < 4; g4++) {
                    W[g4][0] = cvtpk(s[kt][4 * g4], s[kt][4 * g4 + 1]);
                    W[g4][1] = cvtpk(s[kt][4 * g4 + 2], s[kt][4 * g4 + 3]);
                }
#pragma unroll
                for (int f2 = 0; f2 < 2; f2++) {
                    unsigned a0 = W[2 * f2][0], b0 = W[2 * f2 + 1][0];
                    unsigned a1 = W[2 * f2][1], b1 = W[2 * f2 + 1][1];
                    asm volatile("v_permlane32_swap_b32 %0, %1" : "+v"(a0), "+v"(b0));
                    asm volatile("v_permlane32_swap_b32 %0, %1" : "+v"(a1), "+v"(b1));
                    union { unsigned u[4]; bf16x8 v; } bp;
                    bp.u[0] = a0; bp.u[1] = a1; bp.u[2] = b0; bp.u[3] = b1;
#pragma unroll
                    for (int dt = 0; dt < 2; dt++) {
                        bf16x8 aV = *(const bf16x8*)(Vt + swz(dt * 32 + q31, kt * 4 + f2 * 2 + hb));
                        o[dt] = __builtin_amdgcn_mfma_f32_32x32x16_bf16(aV, bp.v, o[dt], 0, 0, 0);
                    }
                }
            }
            __builtin_amdgcn_s_setprio(0);
        }
        __syncthreads();   // drains next-chunk loads (after compute) + guards buffer reuse
    }
    size_t pb = (size_t)(bh * NSEG + sg) * TT;
    float inv = 1.f / ls;
#pragma unroll
    for (int dt = 0; dt < 2; dt++)
#pragma unroll
        for (int g4 = 0; g4 < 4; g4++) {
            u16x4 pk4;
#pragma unroll
            for (int c = 0; c < 4; c++) pk4[c] = f2bf(o[dt][4 * g4 + c] * inv);
            *(u16x4*)(op + (pb + myq) * DD + dt * 32 + 8 * g4 + 4 * hb) = pk4;
        }
    if (hb == 0) {
        mb[pb + myq] = m_;
        lb[pb + myq] = ls;
    }
}

// merge partials (weights computed inline, base-2 domain) + combine with rr branch
__global__ void merge_kernel(const u16* __restrict__ op,
                             const float* __restrict__ mb, const float* __restrict__ lb,
                             const u16* __restrict__ outr, const float* __restrict__ alpha,
                             u16* __restrict__ comb) {
    int i8 = blockIdx.x * blockDim.x + threadIdx.x;
    if (i8 >= M4 * EE / 8) return;
    int bt = i8 / (EE / 8), c8 = i8 - bt * (EE / 8);
    int h = c8 >> 3, d8 = c8 & 7;
    int b = bt >> 11, t = bt & 2047;
    int bh = b * HH + h;
    int ns = (t >> 9) + 1;
    size_t base = (size_t)bh * NSEG * TT + t;
    float M = -INFINITY;
    for (int s = 0; s < ns; s++) M = fmaxf(M, mb[base + (size_t)s * TT]);
    float e[NSEG], L = 0.f;
    for (int s = 0; s < ns; s++) {
        e[s] = lb[base + (size_t)s * TT] * fexp2(mb[base + (size_t)s * TT] - M);
        L += e[s];
    }
    float invL = 1.f / L;
    float acc[8] = {};
    for (int s = 0; s < ns; s++) {
        size_t row = base + (size_t)s * TT;
        float wv = e[s] * invL;
        union { u16 u[8]; bf16x8 v; } pv;
        pv.v = *(const bf16x8*)(op + row * DD + d8 * 8);
#pragma unroll
        for (int ee = 0; ee < 8; ee++) acc[ee] += wv * bf2f(pv.u[ee]);
    }
    float a = 1.f / (1.f + __expf(-alpha[h]));
    union { u16 u[8]; bf16x8 v; } vr, vo;
    vr.v = *(const bf16x8*)(outr + (((size_t)bh * TT + t) * DD + d8 * 8));
#pragma unroll
    for (int ee = 0; ee < 8; ee++)
        vo.u[ee] = f2bf(a * bf2f(vr.u[ee]) + (1.f - a) * acc[ee]);
    ((bf16x8*)comb)[i8] = vo.v;
}

// ---------------------------------------------------------------- output GEMM (m97 structure)
__global__ __launch_bounds__(256) void gemm_out_kernel(const u16* __restrict__ A,
                                                       const u16* __restrict__ Bt,
                                                       float* __restrict__ C) {
    __shared__ __align__(16) u16 As[128 * 32];
    __shared__ __align__(16) u16 Bs[128 * 32];
    const int K = EE;
    int tid = threadIdx.x;
    int w = tid >> 6, l = tid & 63;
    int lo = l & 15, hi = l >> 4;
    int wm = w >> 1, wn = w & 1;
    int m0 = blockIdx.x * 128;
    int n0 = blockIdx.y * 128;
    int srow = l >> 2, sgrp = l & 3;

    f32x4 acc[4][4] = {};
    for (int k0 = 0; k0 < K; k0 += 32) {
        __syncthreads();
        gld_lds16(A + (size_t)(m0 + w * 16 + srow) * K + k0 + sgrp * 8,       As + w * 512);
        gld_lds16(A + (size_t)(m0 + (w + 4) * 16 + srow) * K + k0 + sgrp * 8, As + (w + 4) * 512);
        gld_lds16(Bt + (size_t)(n0 + w * 16 + srow) * K + k0 + sgrp * 8,       Bs + w * 512);
        gld_lds16(Bt + (size_t)(n0 + (w + 4) * 16 + srow) * K + k0 + sgrp * 8, Bs + (w + 4) * 512);
        __syncthreads();
        bf16x8 af[4], bfr[4];
#pragma unroll
        for (int i = 0; i < 4; i++)
            af[i] = *(const bf16x8*)(As + (wm * 64 + i * 16 + lo) * 32 + hi * 8);
#pragma unroll
        for (int j = 0; j < 4; j++)
            bfr[j] = *(const bf16x8*)(Bs + (wn * 64 + j * 16 + lo) * 32 + hi * 8);
#pragma unroll
        for (int i = 0; i < 4; i++)
#pragma unroll
            for (int j = 0; j < 4; j++)
                acc[i][j] = __builtin_amdgcn_mfma_f32_16x16x32_bf16(af[i], bfr[j], acc[i][j], 0, 0, 0);
    }
#pragma unroll
    for (int i = 0; i < 4; i++)
#pragma unroll
        for (int j = 0; j < 4; j++)
#pragma unroll
            for (int r = 0; r < 4; r++) {
                int m = m0 + wm * 64 + i * 16 + hi * 4 + r;
                int n = n0 + wn * 64 + j * 16 + lo;
                C[(size_t)m * EE + n] = acc[i][j][r];
            }
}

// ----------------------------------------------------------------
extern "C" void kernel_launch(void* const* d_in, const int* in_sizes, int n_in,
                              void* d_out, int out_size, void* d_ws, size_t ws_size,
                              hipStream_t stream) {
    const float* x = (const float*)d_in[0];
    const float* wq = (const float*)d_in[1];
    const float* wk = (const float*)d_in[2];
    const float* wv = (const float*)d_in[3];
    const float* wr = (const float*)d_in[4];
    const float* alpha = (const float*)d_in[5];
    const float* wo = (const float*)d_in[6];
    float* out = (float*)d_out;

    char* ws = (char*)d_ws;
    size_t off = 0;
    auto carve = [&](size_t bytes) -> char* {
        char* p = ws + off;
        off += (bytes + 255) & ~(size_t)255;
        return p;
    };
    u16* xb    = (u16*)carve((size_t)M4 * EE * 2);
    u16* wqkvt = (u16*)carve((size_t)NQKV * EE * 2);
    u16* wot   = (u16*)carve((size_t)EE * EE * 2);
    u16* qb    = (u16*)carve((size_t)BH * TT * DD * 2);
    u16* kb    = (u16*)carve((size_t)BH * TT * DD * 2);
    u16* vb    = (u16*)carve((size_t)BH * TT * DD * 2);
    u16* vt    = (u16*)carve((size_t)BH * TT * DD * 2);
    float* xt   = (float*)carve((size_t)BB * EE * TT * 4);
    float* rpbuf= (float*)carve((size_t)48 * BH * TT * 4);
    float* rbuf = (float*)carve((size_t)BH * TT * 4);
    float* rmx  = (float*)carve((size_t)BH * 4);
    float* Sv   = (float*)carve((size_t)BH * SCH * DD * 4);
    float* Sl   = (float*)carve((size_t)BH * SCH * 4);
    u16* outr  = (u16*)carve((size_t)BH * TT * DD * 2);
    u16* opart = (u16*)carve((size_t)BH * NSEG * TT * DD * 2);
    float* mbuf = (float*)carve((size_t)BH * NSEG * TT * 4);
    float* lbuf = (float*)carve((size_t)BH * NSEG * TT * 4);
    u16* comb  = (u16*)carve((size_t)M4 * EE * 2);

    transpose_x_kernel<<<dim3(TT / 32, EE / 32, BB), 256, 0, stream>>>(x, xt, xb);
    transpose_w_kernel<<<dim3(EE / 32, EE / 32, 4), 256, 0, stream>>>(wq, wk, wv, wo, wqkvt, wot);

    dim3 gq(M4 / 128, NQKV / 128);
    gemm_qkv_kernel<<<gq, 256, 0, stream>>>(xb, wqkvt, qb, kb, vb, vt);

    r_partial_kernel<<<dim3(48, 2, 2), 256, 0, stream>>>(xt, wr, rpbuf);
    r_reduce_kernel<<<BH, 256, 0, stream>>>(rpbuf, rbuf, rmx);

    scan_part_kernel<<<dim3(SCH, BH), 64, 0, stream>>>(rbuf, rmx, vb, Sv, Sl);
    scan_out_kernel<<<dim3(SCH, BH), 64, 0, stream>>>(rbuf, rmx, vb, Sv, Sl, outr);

    flash_kernel<<<dim3(TT / QBLK, NSEG, BH), 256, 0, stream>>>(qb, kb, vt, opart, mbuf, lbuf);
    merge_kernel<<<(M4 * EE / 8 + 255) / 256, 256, 0, stream>>>(opart, mbuf, lbuf, outr, alpha, comb);

    dim3 go(M4 / 128, EE / 128);
    gemm_out_kernel<<<go, 256, 0, stream>>>(comb, wot, out);
}

// Round 13
// 155.367 us; speedup vs baseline: 1.1407x; 1.0318x over previous
//
#include <hip/hip_runtime.h>
#include <math.h>

typedef __bf16 bf16x8 __attribute__((ext_vector_type(8)));
typedef float f32x4 __attribute__((ext_vector_type(4)));
typedef float f32x16 __attribute__((ext_vector_type(16)));
typedef unsigned short u16;
typedef unsigned short u16x4 __attribute__((ext_vector_type(4)));

#define BB 2
#define TT 2048
#define EE 768
#define HH 12
#define DD 64
#define BH (BB*HH)      /* 24 */
#define M4 (BB*TT)      /* 4096 */
#define NQKV (3*EE)     /* 2304 */
#define SCH 16          /* scan chunks (128 t each) */
#define KSEG 512        /* flash split-K segment */
#define NSEG (TT/KSEG)  /* 4 */
#define KVB 64
#define QBLK 128

__device__ __forceinline__ u16 f2bf(float f) {
    union { float f; unsigned u; } v; v.f = f;
    unsigned r = v.u + 0x7FFFu + ((v.u >> 16) & 1u);
    return (u16)(r >> 16);
}
__device__ __forceinline__ float bf2f(u16 u) {
    union { unsigned u; float f; } v; v.u = ((unsigned)u) << 16;
    return v.f;
}
// 2^x via the trans pipe directly
__device__ __forceinline__ float fexp2(float x) {
    float r;
    asm("v_exp_f32 %0, %1" : "=v"(r) : "v"(x));
    return r;
}
// pack two f32 -> u32 of 2 bf16 (lo = a, hi = b), RTNE
__device__ __forceinline__ unsigned cvtpk(float a, float b) {
    unsigned r;
    asm("v_cvt_pk_bf16_f32 %0, %1, %2" : "=v"(r) : "v"(a), "v"(b));
    return r;
}
// u16 index of 8-elem group `grp` in row `row` of a [*,64] u16 LDS tile, XOR-swizzled
__device__ __forceinline__ int swz(int row, int grp) {
    return row * 64 + ((grp ^ (row & 7)) << 3);
}
// async global->LDS, 16B per lane; lds base must be wave-uniform
__device__ __forceinline__ void gld_lds16(const u16* g, u16* l) {
    __builtin_amdgcn_global_load_lds(
        (const __attribute__((address_space(1))) unsigned int*)(const void*)g,
        (__attribute__((address_space(3))) unsigned int*)(void*)l,
        16, 0, 0);
}

// ---------------------------------------------------------------- x: transpose (f32) + straight cast (bf16)
__global__ __launch_bounds__(256) void transpose_x_kernel(
    const float* __restrict__ x, float* __restrict__ xt, u16* __restrict__ xb) {
    __shared__ float tile[32][33];
    int t0 = blockIdx.x * 32, e0 = blockIdx.y * 32, b = blockIdx.z;
    int tx = threadIdx.x & 31, ty = threadIdx.x >> 5;
#pragma unroll
    for (int i = 0; i < 4; i++) {
        size_t idx = ((size_t)b * TT + t0 + ty + 8 * i) * EE + e0 + tx;
        float v = x[idx];
        tile[ty + 8 * i][tx] = v;
        xb[idx] = f2bf(v);
    }
    __syncthreads();
#pragma unroll
    for (int i = 0; i < 4; i++)
        xt[((size_t)b * EE + e0 + ty + 8 * i) * TT + t0 + tx] = tile[tx][ty + 8 * i];
}

// 4 weight transposes in one launch: z=0..2 -> wqkvt slabs, z=3 -> wot
__global__ __launch_bounds__(256) void transpose_w_kernel(
    const float* __restrict__ wq, const float* __restrict__ wk,
    const float* __restrict__ wv, const float* __restrict__ wo,
    u16* __restrict__ wqkvt, u16* __restrict__ wot) {
    __shared__ float tile[32][33];
    int z = blockIdx.z;
    const float* src = (z == 0) ? wq : (z == 1) ? wk : (z == 2) ? wv : wo;
    u16* dst = (z < 3) ? (wqkvt + (size_t)z * EE * EE) : wot;
    int n0 = blockIdx.x * 32, k0 = blockIdx.y * 32;
    int tx = threadIdx.x & 31, ty = threadIdx.x >> 5;
#pragma unroll
    for (int i = 0; i < 4; i++)
        tile[ty + 8 * i][tx] = src[(size_t)(k0 + ty + 8 * i) * EE + n0 + tx];
    __syncthreads();
#pragma unroll
    for (int i = 0; i < 4; i++)
        dst[(size_t)(n0 + ty + 8 * i) * EE + k0 + tx] = f2bf(tile[tx][ty + 8 * i]);
}

// ---------------------------------------------------------------- QKV GEMM (m97 structure)
// Also writes vt[bh][d][t] directly from the V epilogue (4 consecutive t per lane).
__global__ __launch_bounds__(256) void gemm_qkv_kernel(
    const u16* __restrict__ A, const u16* __restrict__ Bt,
    u16* __restrict__ qb, u16* __restrict__ kb, u16* __restrict__ vb,
    u16* __restrict__ vt)
{
    __shared__ __align__(16) u16 As[128 * 32];
    __shared__ __align__(16) u16 Bs[128 * 32];
    const int K = EE;
    int tid = threadIdx.x;
    int w = tid >> 6, l = tid & 63;
    int lo = l & 15, hi = l >> 4;
    int wm = w >> 1, wn = w & 1;
    int m0 = blockIdx.x * 128;
    int n0 = blockIdx.y * 128;
    int srow = l >> 2, sgrp = l & 3;

    f32x4 acc[4][4] = {};
    for (int k0 = 0; k0 < K; k0 += 32) {
        __syncthreads();
        gld_lds16(A + (size_t)(m0 + w * 16 + srow) * K + k0 + sgrp * 8,       As + w * 512);
        gld_lds16(A + (size_t)(m0 + (w + 4) * 16 + srow) * K + k0 + sgrp * 8, As + (w + 4) * 512);
        gld_lds16(Bt + (size_t)(n0 + w * 16 + srow) * K + k0 + sgrp * 8,       Bs + w * 512);
        gld_lds16(Bt + (size_t)(n0 + (w + 4) * 16 + srow) * K + k0 + sgrp * 8, Bs + (w + 4) * 512);
        __syncthreads();
        bf16x8 af[4], bfr[4];
#pragma unroll
        for (int i = 0; i < 4; i++)
            af[i] = *(const bf16x8*)(As + (wm * 64 + i * 16 + lo) * 32 + hi * 8);
#pragma unroll
        for (int j = 0; j < 4; j++)
            bfr[j] = *(const bf16x8*)(Bs + (wn * 64 + j * 16 + lo) * 32 + hi * 8);
#pragma unroll
        for (int i = 0; i < 4; i++)
#pragma unroll
            for (int j = 0; j < 4; j++)
                acc[i][j] = __builtin_amdgcn_mfma_f32_16x16x32_bf16(af[i], bfr[j], acc[i][j], 0, 0, 0);
    }
    int sel = n0 / EE;
    int rem0 = n0 - sel * EE;
    u16* dst = (sel == 0) ? qb : (sel == 1) ? kb : vb;
    // q pre-scaled by 1/sqrt(D) * log2(e) so flash can use exp2 directly
    float mul = (sel == 0) ? 0.125f * 1.44269504f : 1.f;
#pragma unroll
    for (int j = 0; j < 4; j++) {
        int h = (rem0 + wn * 64 + j * 16) >> 6;
        int d = (wn * 64 + j * 16 + lo) & 63;
#pragma unroll
        for (int i = 0; i < 4; i++) {
            u16x4 pk4;
#pragma unroll
            for (int r = 0; r < 4; r++) {
                int m = m0 + wm * 64 + i * 16 + hi * 4 + r;
                int b = m >> 11, t = m & 2047;
                u16 val = f2bf(acc[i][j][r] * mul);
                pk4[r] = val;
                dst[((size_t)(b * HH + h) * TT + t) * DD + d] = val;
            }
            if (sel == 2) {
                int mbase = m0 + wm * 64 + i * 16 + hi * 4;
                int b = mbase >> 11, t = mbase & 2047;
                *(u16x4*)(vt + ((size_t)(b * HH + h) * DD + d) * TT + t) = pk4;
            }
        }
    }
}

// ---------------------------------------------------------------- r = scale * x . wr
// grid (48 e-chunks, 2 t-halves, 4 h-groups of 3) = 384 blocks
__global__ __launch_bounds__(256) void r_partial_kernel(
    const float* __restrict__ xt, const float* __restrict__ wr, float* __restrict__ rp) {
    int ech = blockIdx.x;           // 0..47
    int tch = blockIdx.y;           // 0..1
    int hg = blockIdx.z;            // 0..3
    int e0 = ech * 16, h0 = hg * 3;
    int tv = tch * 256 + threadIdx.x;
    const f32x4* xt4 = (const f32x4*)xt;
    const f32x4* wr4 = (const f32x4*)wr;
    f32x4 acc[2][3] = {};
#pragma unroll 4
    for (int e = 0; e < 16; e++) {
        f32x4 x0 = xt4[(size_t)(e0 + e) * 512 + tv];
        f32x4 x1 = xt4[(size_t)(EE + e0 + e) * 512 + tv];
#pragma unroll
        for (int hh = 0; hh < 3; hh++) {
            f32x4 w = wr4[((size_t)(h0 + hh) * EE + e0 + e) * 512 + tv];
            acc[0][hh] += w * x0;
            acc[1][hh] += w * x1;
        }
    }
    f32x4* rp4 = (f32x4*)rp;
#pragma unroll
    for (int b = 0; b < 2; b++)
#pragma unroll
        for (int hh = 0; hh < 3; hh++)
            rp4[((size_t)ech * 24 + b * 12 + h0 + hh) * 512 + tv] = acc[b][hh];
}

// grid (24 bh, 8 t-chunks) = 192 blocks; writes r + per-chunk max rmxp[bh][8]
__global__ __launch_bounds__(256) void r_reduce_kernel(
    const float* __restrict__ rp, float* __restrict__ r, float* __restrict__ rmxp) {
    int bh = blockIdx.x, tch = blockIdx.y, tid = threadIdx.x;
    int t = tch * 256 + tid;
    float s = 0.f;
#pragma unroll 8
    for (int ech = 0; ech < 48; ech++)
        s += rp[((size_t)(ech * 24 + bh)) * TT + t];
    s *= 0.125f;
    r[(size_t)bh * TT + t] = s;
    __shared__ float sm[256];
    sm[tid] = s; __syncthreads();
    for (int st = 128; st > 0; st >>= 1) {
        if (tid < st) sm[tid] = fmaxf(sm[tid], sm[tid + st]);
        __syncthreads();
    }
    if (tid == 0) rmxp[bh * 8 + tch] = sm[0];
}

// ---------------------------------------------------------------- rr attention = chunked prefix scan
__global__ __launch_bounds__(64) void scan_part_kernel(
    const float* __restrict__ r, const float* __restrict__ rmxp,
    const u16* __restrict__ vb, float* __restrict__ Sv, float* __restrict__ Sl) {
    int c = blockIdx.x, bh = blockIdx.y, d = threadIdx.x;
    float mx = rmxp[bh * 8];
#pragma unroll
    for (int i = 1; i < 8; i++) mx = fmaxf(mx, rmxp[bh * 8 + i]);
    const float* rp = r + (size_t)bh * TT + c * 128;
    const u16* vp = vb + ((size_t)bh * TT + c * 128) * DD + d;
    float accv = 0.f, accl = 0.f;
#pragma unroll 4
    for (int j = 0; j < 128; j++) {
        float w = __expf(rp[j] - mx);
        accv += w * bf2f(vp[(size_t)j * DD]);
        accl += w;
    }
    Sv[((size_t)bh * SCH + c) * DD + d] = accv;
    if (d == 0) Sl[bh * SCH + c] = accl;
}

__global__ __launch_bounds__(64) void scan_out_kernel(
    const float* __restrict__ r, const float* __restrict__ rmxp,
    const u16* __restrict__ vb, const float* __restrict__ Sv, const float* __restrict__ Sl,
    u16* __restrict__ outr) {
    int c = blockIdx.x, bh = blockIdx.y, d = threadIdx.x;
    float mx = rmxp[bh * 8];
#pragma unroll
    for (int i = 1; i < 8; i++) mx = fmaxf(mx, rmxp[bh * 8 + i]);
    float acc = 0.f, accl = 0.f;
    for (int cp = 0; cp < c; cp++) {
        acc += Sv[((size_t)bh * SCH + cp) * DD + d];
        accl += Sl[bh * SCH + cp];
    }
    const float* rp = r + (size_t)bh * TT + c * 128;
    const u16* vp = vb + ((size_t)bh * TT + c * 128) * DD + d;
    u16* op = outr + ((size_t)bh * TT + c * 128) * DD + d;
#pragma unroll 2
    for (int j = 0; j < 128; j++) {
        float w = __expf(rp[j] - mx);
        acc += w * bf2f(vp[(size_t)j * DD]);
        accl += w;
        op[(size_t)j * DD] = f2bf(acc * __builtin_amdgcn_rcpf(accl));
    }
}

// ---------------------------------------------------------------- content flash attention, split-K, 32x32 MFMA
// Double-buffered async K/V staging (global_load_lds, pre-swizzled global src).
// S^T = mfma32(K, Q): lane owns q = qw0 + (l&31); softmax in-register; defer-max THR=8.
// Tree reductions for tile-max and row-sum (break the 31-op serial chains).
// P^T B-frags via cvt_pk + permlane32_swap. PV: O^T = mfma32(V^T, P^T).
__global__ __launch_bounds__(256) void flash_kernel(
    const u16* __restrict__ qb, const u16* __restrict__ kb,
    const u16* __restrict__ vt, u16* __restrict__ op,
    float* __restrict__ mb, float* __restrict__ lb) {
    __shared__ __align__(16) u16 KV[2][2][64 * 64];   // [buf][K/V][row*64]
    int qt = (int)gridDim.x - 1 - (int)blockIdx.x;   // heavy tiles first
    int sg = blockIdx.y, bh = blockIdx.z;
    int q0 = qt * QBLK;
    int ks0 = sg * KSEG;
    if (ks0 > q0) return;                   // segment has no causal keys for this tile
    int kend = min(ks0 + KSEG, q0 + QBLK);
    int nc = (kend - ks0) >> 6;
    int tid = threadIdx.x, w = tid >> 6, l = tid & 63;
    int q31 = l & 31, hb = l >> 5;
    int qw0 = q0 + w * 32;
    int myq = qw0 + q31;
    const u16* qbase = qb + (size_t)bh * TT * DD;
    const u16* kbase = kb + (size_t)bh * TT * DD;
    const u16* vtb = vt + (size_t)bh * DD * TT;

    // staging coords: lane -> (row, slot); global src pre-swizzled so linear LDS dest
    // matches the swz() read pattern
    int sr0 = w * 8 + (l >> 3);
    int sg8 = (((l & 7) ^ (sr0 & 7)) << 3);
    auto stage = [&](int j0, int bbuf) {
        u16* kd = &KV[bbuf][0][0];
        u16* vd = &KV[bbuf][1][0];
        gld_lds16(kbase + (size_t)(j0 + sr0) * DD + sg8,      kd + w * 512);
        gld_lds16(kbase + (size_t)(j0 + sr0 + 32) * DD + sg8, kd + 2048 + w * 512);
        gld_lds16(vtb + (size_t)sr0 * TT + j0 + sg8,          vd + w * 512);
        gld_lds16(vtb + (size_t)(sr0 + 32) * TT + j0 + sg8,   vd + 2048 + w * 512);
    };

    // Q B-frags: col=q, k(d) = mm*16 + hb*8 + e
    bf16x8 bQ[4];
#pragma unroll
    for (int mm = 0; mm < 4; mm++)
        bQ[mm] = *(const bf16x8*)(qbase + (size_t)myq * DD + mm * 16 + hb * 8);

    float m_ = -INFINITY, ls = 0.f;
    f32x16 o[2] = {};

    stage(ks0, 0);
    __syncthreads();
    for (int ci = 0; ci < nc; ci++) {
        int j0 = ks0 + ci * 64;
        int bbuf = ci & 1;
        if (ci + 1 < nc) stage(j0 + 64, bbuf ^ 1);   // async, overlaps compute below
        if (j0 <= qw0 + 31) {
            const u16* Kt = &KV[bbuf][0][0];
            const u16* Vt = &KV[bbuf][1][0];
            // S^T: s[kt][reg] = score(q=myq, k = j0 + kt*32 + (reg&3)+8*(reg>>2)+4*hb)
            f32x16 s[2] = {};
            __builtin_amdgcn_s_setprio(1);
#pragma unroll
            for (int kt = 0; kt < 2; kt++)
#pragma unroll
                for (int mm = 0; mm < 4; mm++) {
                    bf16x8 aK = *(const bf16x8*)(Kt + swz(kt * 32 + q31, mm * 2 + hb));
                    s[kt] = __builtin_amdgcn_mfma_f32_32x32x16_bf16(aK, bQ[mm], s[kt], 0, 0, 0);
                }
            __builtin_amdgcn_s_setprio(0);
            if (j0 + 63 > qw0) {
#pragma unroll
                for (int kt = 0; kt < 2; kt++)
#pragma unroll
                    for (int reg = 0; reg < 16; reg++) {
                        int k = j0 + kt * 32 + (reg & 3) + 8 * (reg >> 2) + 4 * hb;
                        if (k > myq) s[kt][reg] = -INFINITY;
                    }
            }
            // tile max: pairwise tree (5 levels) instead of 31-op serial chain
            float t16[16];
#pragma unroll
            for (int i = 0; i < 16; i++) t16[i] = fmaxf(s[0][i], s[1][i]);
#pragma unroll
            for (int st = 8; st > 0; st >>= 1)
#pragma unroll
                for (int i = 0; i < 8; i++)
                    if (i < st) t16[i] = fmaxf(t16[i], t16[i + st]);
            float tm = t16[0];
            tm = fmaxf(tm, __shfl_xor(tm, 32, 64));
            // defer-max: only rescale when the new tile max meaningfully exceeds m_
            if (__any(tm > m_ + 8.f)) {
                float mn = fmaxf(m_, tm);
                float f = fexp2(m_ - mn);
                m_ = mn;
                ls *= f;
#pragma unroll
                for (int dt = 0; dt < 2; dt++)
#pragma unroll
                    for (int reg = 0; reg < 16; reg++) o[dt][reg] *= f;
            }
#pragma unroll
            for (int kt = 0; kt < 2; kt++)
#pragma unroll
                for (int reg = 0; reg < 16; reg++)
                    s[kt][reg] = fexp2(s[kt][reg] - m_);
            // row sum: pairwise tree
            float a16[16];
#pragma unroll
            for (int i = 0; i < 16; i++) a16[i] = s[0][i] + s[1][i];
#pragma unroll
            for (int st = 8; st > 0; st >>= 1)
#pragma unroll
                for (int i = 0; i < 8; i++)
                    if (i < st) a16[i] += a16[i + st];
            float rs = a16[0];
            rs += __shfl_xor(rs, 32, 64);
            ls += rs;

            // P^T B-frags + PV
            __builtin_amdgcn_s_setprio(1);
#pragma unroll
            for (int kt = 0; kt < 2; kt++) {
                unsigned W[4][2];
#pragma unroll
                for (int g4 = 0; g4 < 4; g4++) {
                    W[g4][0] = cvtpk(s[kt][4 * g4], s[kt][4 * g4 + 1]);
                    W[g4][1] = cvtpk(s[kt][4 * g4 + 2], s[kt][4 * g4 + 3]);
                }
#pragma unroll
                for (int f2 = 0; f2 < 2; f2++) {
                    unsigned a0 = W[2 * f2][0], b0 = W[2 * f2 + 1][0];
                    unsigned a1 = W[2 * f2][1], b1 = W[2 * f2 + 1][1];
                    asm volatile("v_permlane32_swap_b32 %0, %1" : "+v"(a0), "+v"(b0));
                    asm volatile("v_permlane32_swap_b32 %0, %1" : "+v"(a1), "+v"(b1));
                    union { unsigned u[4]; bf16x8 v; } bp;
                    bp.u[0] = a0; bp.u[1] = a1; bp.u[2] = b0; bp.u[3] = b1;
#pragma unroll
                    for (int dt = 0; dt < 2; dt++) {
                        bf16x8 aV = *(const bf16x8*)(Vt + swz(dt * 32 + q31, kt * 4 + f2 * 2 + hb));
                        o[dt] = __builtin_amdgcn_mfma_f32_32x32x16_bf16(aV, bp.v, o[dt], 0, 0, 0);
                    }
                }
            }
            __builtin_amdgcn_s_setprio(0);
        }
        __syncthreads();   // drains next-chunk loads (after compute) + guards buffer reuse
    }
    size_t pb = (size_t)(bh * NSEG + sg) * TT;
    float inv = 1.f / ls;
#pragma unroll
    for (int dt = 0; dt < 2; dt++)
#pragma unroll
        for (int g4 = 0; g4 < 4; g4++) {
            u16x4 pk4;
#pragma unroll
            for (int c = 0; c < 4; c++) pk4[c] = f2bf(o[dt][4 * g4 + c] * inv);
            *(u16x4*)(op + (pb + myq) * DD + dt * 32 + 8 * g4 + 4 * hb) = pk4;
        }
    if (hb == 0) {
        mb[pb + myq] = m_;
        lb[pb + myq] = ls;
    }
}

// merge partials (weights computed inline, base-2 domain) + combine with rr branch
__global__ void merge_kernel(const u16* __restrict__ op,
                             const float* __restrict__ mb, const float* __restrict__ lb,
                             const u16* __restrict__ outr, const float* __restrict__ alpha,
                             u16* __restrict__ comb) {
    int i8 = blockIdx.x * blockDim.x + threadIdx.x;
    if (i8 >= M4 * EE / 8) return;
    int bt = i8 / (EE / 8), c8 = i8 - bt * (EE / 8);
    int h = c8 >> 3, d8 = c8 & 7;
    int b = bt >> 11, t = bt & 2047;
    int bh = b * HH + h;
    int ns = (t >> 9) + 1;
    size_t base = (size_t)bh * NSEG * TT + t;
    float M = -INFINITY;
    for (int s = 0; s < ns; s++) M = fmaxf(M, mb[base + (size_t)s * TT]);
    float e[NSEG], L = 0.f;
    for (int s = 0; s < ns; s++) {
        e[s] = lb[base + (size_t)s * TT] * fexp2(mb[base + (size_t)s * TT] - M);
        L += e[s];
    }
    float invL = 1.f / L;
    float acc[8] = {};
    for (int s = 0; s < ns; s++) {
        size_t row = base + (size_t)s * TT;
        float wv = e[s] * invL;
        union { u16 u[8]; bf16x8 v; } pv;
        pv.v = *(const bf16x8*)(op + row * DD + d8 * 8);
#pragma unroll
        for (int ee = 0; ee < 8; ee++) acc[ee] += wv * bf2f(pv.u[ee]);
    }
    float a = 1.f / (1.f + __expf(-alpha[h]));
    union { u16 u[8]; bf16x8 v; } vr, vo;
    vr.v = *(const bf16x8*)(outr + (((size_t)bh * TT + t) * DD + d8 * 8));
#pragma unroll
    for (int ee = 0; ee < 8; ee++)
        vo.u[ee] = f2bf(a * bf2f(vr.u[ee]) + (1.f - a) * acc[ee]);
    ((bf16x8*)comb)[i8] = vo.v;
}

// ---------------------------------------------------------------- output GEMM (m97 structure)
__global__ __launch_bounds__(256) void gemm_out_kernel(const u16* __restrict__ A,
                                                       const u16* __restrict__ Bt,
                                                       float* __restrict__ C) {
    __shared__ __align__(16) u16 As[128 * 32];
    __shared__ __align__(16) u16 Bs[128 * 32];
    const int K = EE;
    int tid = threadIdx.x;
    int w = tid >> 6, l = tid & 63;
    int lo = l & 15, hi = l >> 4;
    int wm = w >> 1, wn = w & 1;
    int m0 = blockIdx.x * 128;
    int n0 = blockIdx.y * 128;
    int srow = l >> 2, sgrp = l & 3;

    f32x4 acc[4][4] = {};
    for (int k0 = 0; k0 < K; k0 += 32) {
        __syncthreads();
        gld_lds16(A + (size_t)(m0 + w * 16 + srow) * K + k0 + sgrp * 8,       As + w * 512);
        gld_lds16(A + (size_t)(m0 + (w + 4) * 16 + srow) * K + k0 + sgrp * 8, As + (w + 4) * 512);
        gld_lds16(Bt + (size_t)(n0 + w * 16 + srow) * K + k0 + sgrp * 8,       Bs + w * 512);
        gld_lds16(Bt + (size_t)(n0 + (w + 4) * 16 + srow) * K + k0 + sgrp * 8, Bs + (w + 4) * 512);
        __syncthreads();
        bf16x8 af[4], bfr[4];
#pragma unroll
        for (int i = 0; i < 4; i++)
            af[i] = *(const bf16x8*)(As + (wm * 64 + i * 16 + lo) * 32 + hi * 8);
#pragma unroll
        for (int j = 0; j < 4; j++)
            bfr[j] = *(const bf16x8*)(Bs + (wn * 64 + j * 16 + lo) * 32 + hi * 8);
#pragma unroll
        for (int i = 0; i < 4; i++)
#pragma unroll
            for (int j = 0; j < 4; j++)
                acc[i][j] = __builtin_amdgcn_mfma_f32_16x16x32_bf16(af[i], bfr[j], acc[i][j], 0, 0, 0);
    }
#pragma unroll
    for (int i = 0; i < 4; i++)
#pragma unroll
        for (int j = 0; j < 4; j++)
#pragma unroll
            for (int r = 0; r < 4; r++) {
                int m = m0 + wm * 64 + i * 16 + hi * 4 + r;
                int n = n0 + wn * 64 + j * 16 + lo;
                C[(size_t)m * EE + n] = acc[i][j][r];
            }
}

// ----------------------------------------------------------------
extern "C" void kernel_launch(void* const* d_in, const int* in_sizes, int n_in,
                              void* d_out, int out_size, void* d_ws, size_t ws_size,
                              hipStream_t stream) {
    const float* x = (const float*)d_in[0];
    const float* wq = (const float*)d_in[1];
    const float* wk = (const float*)d_in[2];
    const float* wv = (const float*)d_in[3];
    const float* wr = (const float*)d_in[4];
    const float* alpha = (const float*)d_in[5];
    const float* wo = (const float*)d_in[6];
    float* out = (float*)d_out;

    char* ws = (char*)d_ws;
    size_t off = 0;
    auto carve = [&](size_t bytes) -> char* {
        char* p = ws + off;
        off += (bytes + 255) & ~(size_t)255;
        return p;
    };
    u16* xb    = (u16*)carve((size_t)M4 * EE * 2);
    u16* wqkvt = (u16*)carve((size_t)NQKV * EE * 2);
    u16* wot   = (u16*)carve((size_t)EE * EE * 2);
    u16* qb    = (u16*)carve((size_t)BH * TT * DD * 2);
    u16* kb    = (u16*)carve((size_t)BH * TT * DD * 2);
    u16* vb    = (u16*)carve((size_t)BH * TT * DD * 2);
    u16* vt    = (u16*)carve((size_t)BH * TT * DD * 2);
    float* xt   = (float*)carve((size_t)BB * EE * TT * 4);
    float* rpbuf= (float*)carve((size_t)48 * BH * TT * 4);
    float* rbuf = (float*)carve((size_t)BH * TT * 4);
    float* rmxp = (float*)carve((size_t)BH * 8 * 4);
    float* Sv   = (float*)carve((size_t)BH * SCH * DD * 4);
    float* Sl   = (float*)carve((size_t)BH * SCH * 4);
    u16* outr  = (u16*)carve((size_t)BH * TT * DD * 2);
    u16* opart = (u16*)carve((size_t)BH * NSEG * TT * DD * 2);
    float* mbuf = (float*)carve((size_t)BH * NSEG * TT * 4);
    float* lbuf = (float*)carve((size_t)BH * NSEG * TT * 4);
    u16* comb  = (u16*)carve((size_t)M4 * EE * 2);

    transpose_x_kernel<<<dim3(TT / 32, EE / 32, BB), 256, 0, stream>>>(x, xt, xb);
    transpose_w_kernel<<<dim3(EE / 32, EE / 32, 4), 256, 0, stream>>>(wq, wk, wv, wo, wqkvt, wot);

    dim3 gq(M4 / 128, NQKV / 128);
    gemm_qkv_kernel<<<gq, 256, 0, stream>>>(xb, wqkvt, qb, kb, vb, vt);

    r_partial_kernel<<<dim3(48, 2, 4), 256, 0, stream>>>(xt, wr, rpbuf);
    r_reduce_kernel<<<dim3(BH, 8), 256, 0, stream>>>(rpbuf, rbuf, rmxp);

    scan_part_kernel<<<dim3(SCH, BH), 64, 0, stream>>>(rbuf, rmxp, vb, Sv, Sl);
    scan_out_kernel<<<dim3(SCH, BH), 64, 0, stream>>>(rbuf, rmxp, vb, Sv, Sl, outr);

    flash_kernel<<<dim3(TT / QBLK, NSEG, BH), 256, 0, stream>>>(qb, kb, vt, opart, mbuf, lbuf);
    merge_kernel<<<(M4 * EE / 8 + 255) / 256, 256, 0, stream>>>(opart, mbuf, lbuf, outr, alpha, comb);

    dim3 go(M4 / 128, EE / 128);
    gemm_out_kernel<<<go, 256, 0, stream>>>(comb, wot, out);
}

// Round 14
// 148.791 us; speedup vs baseline: 1.1911x; 1.0442x over previous
//
#include <hip/hip_runtime.h>
#include <math.h>

typedef __bf16 bf16x8 __attribute__((ext_vector_type(8)));
typedef float f32x4 __attribute__((ext_vector_type(4)));
typedef float f32x16 __attribute__((ext_vector_type(16)));
typedef unsigned short u16;
typedef unsigned short u16x4 __attribute__((ext_vector_type(4)));

#define BB 2
#define TT 2048
#define EE 768
#define HH 12
#define DD 64
#define BH (BB*HH)      /* 24 */
#define M4 (BB*TT)      /* 4096 */
#define NQKV (3*EE)     /* 2304 */
#define SCH 16          /* scan chunks (128 t each) */
#define KSEG 512        /* flash split-K segment */
#define NSEG (TT/KSEG)  /* 4 */
#define KVB 64
#define QBLK 128

__device__ __forceinline__ u16 f2bf(float f) {
    union { float f; unsigned u; } v; v.f = f;
    unsigned r = v.u + 0x7FFFu + ((v.u >> 16) & 1u);
    return (u16)(r >> 16);
}
__device__ __forceinline__ float bf2f(u16 u) {
    union { unsigned u; float f; } v; v.u = ((unsigned)u) << 16;
    return v.f;
}
// 2^x via the trans pipe directly
__device__ __forceinline__ float fexp2(float x) {
    float r;
    asm("v_exp_f32 %0, %1" : "=v"(r) : "v"(x));
    return r;
}
// pack two f32 -> u32 of 2 bf16 (lo = a, hi = b), RTNE
__device__ __forceinline__ unsigned cvtpk(float a, float b) {
    unsigned r;
    asm("v_cvt_pk_bf16_f32 %0, %1, %2" : "=v"(r) : "v"(a), "v"(b));
    return r;
}
// u16 index of 8-elem group `grp` in row `row` of a [*,64] u16 LDS tile, XOR-swizzled
__device__ __forceinline__ int swz(int row, int grp) {
    return row * 64 + ((grp ^ (row & 7)) << 3);
}
// async global->LDS, 16B per lane; lds base must be wave-uniform
__device__ __forceinline__ void gld_lds16(const u16* g, u16* l) {
    __builtin_amdgcn_global_load_lds(
        (const __attribute__((address_space(1))) unsigned int*)(const void*)g,
        (__attribute__((address_space(3))) unsigned int*)(void*)l,
        16, 0, 0);
}

// ---------------------------------------------------------------- fused transposes
// z = 0,1: x batch z -> xt (f32 transpose) + xb (bf16 cast)
// z = 2..5: weight z-2 (wq,wk,wv,wo) -> bf16 transpose
__global__ __launch_bounds__(256) void transpose_all_kernel(
    const float* __restrict__ x,
    const float* __restrict__ wq, const float* __restrict__ wk,
    const float* __restrict__ wv, const float* __restrict__ wo,
    float* __restrict__ xt, u16* __restrict__ xb,
    u16* __restrict__ wqkvt, u16* __restrict__ wot)
{
    __shared__ float tile[32][33];
    int z = blockIdx.z;
    int tx = threadIdx.x & 31, ty = threadIdx.x >> 5;
    if (z < 2) {
        int t0 = blockIdx.x * 32, e0 = blockIdx.y * 32, b = z;
#pragma unroll
        for (int i = 0; i < 4; i++) {
            size_t idx = ((size_t)b * TT + t0 + ty + 8 * i) * EE + e0 + tx;
            float v = x[idx];
            tile[ty + 8 * i][tx] = v;
            xb[idx] = f2bf(v);
        }
        __syncthreads();
#pragma unroll
        for (int i = 0; i < 4; i++)
            xt[((size_t)b * EE + e0 + ty + 8 * i) * TT + t0 + tx] = tile[tx][ty + 8 * i];
    } else {
        if (blockIdx.x >= EE / 32) return;
        int zz = z - 2;
        const float* src = (zz == 0) ? wq : (zz == 1) ? wk : (zz == 2) ? wv : wo;
        u16* dst = (zz < 3) ? (wqkvt + (size_t)zz * EE * EE) : wot;
        int n0 = blockIdx.x * 32, k0 = blockIdx.y * 32;
#pragma unroll
        for (int i = 0; i < 4; i++)
            tile[ty + 8 * i][tx] = src[(size_t)(k0 + ty + 8 * i) * EE + n0 + tx];
        __syncthreads();
#pragma unroll
        for (int i = 0; i < 4; i++)
            dst[(size_t)(n0 + ty + 8 * i) * EE + k0 + tx] = f2bf(tile[tx][ty + 8 * i]);
    }
}

// ---------------------------------------------------------------- QKV GEMM (m97, BK=64, swizzled LDS)
// Also writes vt[bh][d][t] directly from the V epilogue.
__global__ __launch_bounds__(256) void gemm_qkv_kernel(
    const u16* __restrict__ A, const u16* __restrict__ Bt,
    u16* __restrict__ qb, u16* __restrict__ kb, u16* __restrict__ vb,
    u16* __restrict__ vt)
{
    __shared__ __align__(16) u16 As[128 * 64];
    __shared__ __align__(16) u16 Bs[128 * 64];
    const int K = EE;
    int tid = threadIdx.x;
    int w = tid >> 6, l = tid & 63;
    int lo = l & 15, hi = l >> 4;
    int wm = w >> 1, wn = w & 1;
    int m0 = blockIdx.x * 128;
    int n0 = blockIdx.y * 128;
    int srow = l >> 3;                         // row within 8-row chunk
    int sgx = ((l & 7) ^ (srow & 7)) * 8;      // pre-swizzled source col (u16)

    f32x4 acc[4][4] = {};
    for (int k0 = 0; k0 < K; k0 += 64) {
        __syncthreads();
#pragma unroll
        for (int c4 = 0; c4 < 4; c4++) {
            int c = w * 4 + c4;                // 8-row chunk 0..15
            gld_lds16(A + (size_t)(m0 + c * 8 + srow) * K + k0 + sgx, As + c * 512);
            gld_lds16(Bt + (size_t)(n0 + c * 8 + srow) * K + k0 + sgx, Bs + c * 512);
        }
        __syncthreads();
#pragma unroll
        for (int kk = 0; kk < 2; kk++) {
            bf16x8 af[4], bfr[4];
#pragma unroll
            for (int i = 0; i < 4; i++)
                af[i] = *(const bf16x8*)(As + swz(wm * 64 + i * 16 + lo, kk * 4 + hi));
#pragma unroll
            for (int j = 0; j < 4; j++)
                bfr[j] = *(const bf16x8*)(Bs + swz(wn * 64 + j * 16 + lo, kk * 4 + hi));
#pragma unroll
            for (int i = 0; i < 4; i++)
#pragma unroll
                for (int j = 0; j < 4; j++)
                    acc[i][j] = __builtin_amdgcn_mfma_f32_16x16x32_bf16(af[i], bfr[j], acc[i][j], 0, 0, 0);
        }
    }
    int sel = n0 / EE;
    int rem0 = n0 - sel * EE;
    u16* dst = (sel == 0) ? qb : (sel == 1) ? kb : vb;
    // q pre-scaled by 1/sqrt(D) * log2(e) so flash can use exp2 directly
    float mul = (sel == 0) ? 0.125f * 1.44269504f : 1.f;
#pragma unroll
    for (int j = 0; j < 4; j++) {
        int h = (rem0 + wn * 64 + j * 16) >> 6;
        int d = (wn * 64 + j * 16 + lo) & 63;
#pragma unroll
        for (int i = 0; i < 4; i++) {
            u16x4 pk4;
#pragma unroll
            for (int r = 0; r < 4; r++) {
                int m = m0 + wm * 64 + i * 16 + hi * 4 + r;
                int b = m >> 11, t = m & 2047;
                u16 val = f2bf(acc[i][j][r] * mul);
                pk4[r] = val;
                dst[((size_t)(b * HH + h) * TT + t) * DD + d] = val;
            }
            if (sel == 2) {
                int mbase = m0 + wm * 64 + i * 16 + hi * 4;
                int b = mbase >> 11, t = mbase & 2047;
                *(u16x4*)(vt + ((size_t)(b * HH + h) * DD + d) * TT + t) = pk4;
            }
        }
    }
}

// ---------------------------------------------------------------- r = scale * x . wr
// grid (48 e-chunks, 2 t-halves, 4 h-groups of 3) = 384 blocks
__global__ __launch_bounds__(256) void r_partial_kernel(
    const float* __restrict__ xt, const float* __restrict__ wr, float* __restrict__ rp) {
    int ech = blockIdx.x;
    int tch = blockIdx.y;
    int hg = blockIdx.z;
    int e0 = ech * 16, h0 = hg * 3;
    int tv = tch * 256 + threadIdx.x;
    const f32x4* xt4 = (const f32x4*)xt;
    const f32x4* wr4 = (const f32x4*)wr;
    f32x4 acc[2][3] = {};
#pragma unroll 4
    for (int e = 0; e < 16; e++) {
        f32x4 x0 = xt4[(size_t)(e0 + e) * 512 + tv];
        f32x4 x1 = xt4[(size_t)(EE + e0 + e) * 512 + tv];
#pragma unroll
        for (int hh = 0; hh < 3; hh++) {
            f32x4 w = wr4[((size_t)(h0 + hh) * EE + e0 + e) * 512 + tv];
            acc[0][hh] += w * x0;
            acc[1][hh] += w * x1;
        }
    }
    f32x4* rp4 = (f32x4*)rp;
#pragma unroll
    for (int b = 0; b < 2; b++)
#pragma unroll
        for (int hh = 0; hh < 3; hh++)
            rp4[((size_t)ech * 24 + b * 12 + h0 + hh) * 512 + tv] = acc[b][hh];
}

// grid (24 bh, 8 t-chunks); writes r + per-chunk max rmxp[bh][8]
__global__ __launch_bounds__(256) void r_reduce_kernel(
    const float* __restrict__ rp, float* __restrict__ r, float* __restrict__ rmxp) {
    int bh = blockIdx.x, tch = blockIdx.y, tid = threadIdx.x;
    int t = tch * 256 + tid;
    float s = 0.f;
#pragma unroll 8
    for (int ech = 0; ech < 48; ech++)
        s += rp[((size_t)(ech * 24 + bh)) * TT + t];
    s *= 0.125f;
    r[(size_t)bh * TT + t] = s;
    __shared__ float sm[256];
    sm[tid] = s; __syncthreads();
    for (int st = 128; st > 0; st >>= 1) {
        if (tid < st) sm[tid] = fmaxf(sm[tid], sm[tid + st]);
        __syncthreads();
    }
    if (tid == 0) rmxp[bh * 8 + tch] = sm[0];
}

// ---------------------------------------------------------------- rr attention = chunked prefix scan
__global__ __launch_bounds__(64) void scan_part_kernel(
    const float* __restrict__ r, const float* __restrict__ rmxp,
    const u16* __restrict__ vb, float* __restrict__ Sv, float* __restrict__ Sl) {
    int c = blockIdx.x, bh = blockIdx.y, d = threadIdx.x;
    float mx = rmxp[bh * 8];
#pragma unroll
    for (int i = 1; i < 8; i++) mx = fmaxf(mx, rmxp[bh * 8 + i]);
    const float* rp = r + (size_t)bh * TT + c * 128;
    const u16* vp = vb + ((size_t)bh * TT + c * 128) * DD + d;
    float accv = 0.f, accl = 0.f;
#pragma unroll 4
    for (int j = 0; j < 128; j++) {
        float w = __expf(rp[j] - mx);
        accv += w * bf2f(vp[(size_t)j * DD]);
        accl += w;
    }
    Sv[((size_t)bh * SCH + c) * DD + d] = accv;
    if (d == 0) Sl[bh * SCH + c] = accl;
}

__global__ __launch_bounds__(64) void scan_out_kernel(
    const float* __restrict__ r, const float* __restrict__ rmxp,
    const u16* __restrict__ vb, const float* __restrict__ Sv, const float* __restrict__ Sl,
    u16* __restrict__ outr) {
    int c = blockIdx.x, bh = blockIdx.y, d = threadIdx.x;
    float mx = rmxp[bh * 8];
#pragma unroll
    for (int i = 1; i < 8; i++) mx = fmaxf(mx, rmxp[bh * 8 + i]);
    float acc = 0.f, accl = 0.f;
    for (int cp = 0; cp < c; cp++) {
        acc += Sv[((size_t)bh * SCH + cp) * DD + d];
        accl += Sl[bh * SCH + cp];
    }
    const float* rp = r + (size_t)bh * TT + c * 128;
    const u16* vp = vb + ((size_t)bh * TT + c * 128) * DD + d;
    u16* op = outr + ((size_t)bh * TT + c * 128) * DD + d;
#pragma unroll 2
    for (int j = 0; j < 128; j++) {
        float w = __expf(rp[j] - mx);
        acc += w * bf2f(vp[(size_t)j * DD]);
        accl += w;
        op[(size_t)j * DD] = f2bf(acc * __builtin_amdgcn_rcpf(accl));
    }
}

// ---------------------------------------------------------------- content flash attention, split-K, 32x32 MFMA
// Double-buffered async K/V staging (global_load_lds, pre-swizzled global src).
// S^T = mfma32(K, Q): lane owns q = qw0 + (l&31); softmax in-register; defer-max THR=8.
// P^T B-frags via cvt_pk + permlane32_swap. PV: O^T = mfma32(V^T, P^T).
// s_setprio(1) around MFMA clusters.
__global__ __launch_bounds__(256) void flash_kernel(
    const u16* __restrict__ qb, const u16* __restrict__ kb,
    const u16* __restrict__ vt, u16* __restrict__ op,
    float* __restrict__ mb, float* __restrict__ lb) {
    __shared__ __align__(16) u16 KV[2][2][64 * 64];   // [buf][K/V][row*64]
    int qt = (int)gridDim.x - 1 - (int)blockIdx.x;   // heavy tiles first
    int sg = blockIdx.y, bh = blockIdx.z;
    int q0 = qt * QBLK;
    int ks0 = sg * KSEG;
    if (ks0 > q0) return;                   // segment has no causal keys for this tile
    int kend = min(ks0 + KSEG, q0 + QBLK);
    int nc = (kend - ks0) >> 6;
    int tid = threadIdx.x, w = tid >> 6, l = tid & 63;
    int q31 = l & 31, hb = l >> 5;
    int qw0 = q0 + w * 32;
    int myq = qw0 + q31;
    const u16* qbase = qb + (size_t)bh * TT * DD;
    const u16* kbase = kb + (size_t)bh * TT * DD;
    const u16* vtb = vt + (size_t)bh * DD * TT;

    int sr0 = w * 8 + (l >> 3);
    int sg8 = (((l & 7) ^ (sr0 & 7)) << 3);
    auto stage = [&](int j0, int bbuf) {
        u16* kd = &KV[bbuf][0][0];
        u16* vd = &KV[bbuf][1][0];
        gld_lds16(kbase + (size_t)(j0 + sr0) * DD + sg8,      kd + w * 512);
        gld_lds16(kbase + (size_t)(j0 + sr0 + 32) * DD + sg8, kd + 2048 + w * 512);
        gld_lds16(vtb + (size_t)sr0 * TT + j0 + sg8,          vd + w * 512);
        gld_lds16(vtb + (size_t)(sr0 + 32) * TT + j0 + sg8,   vd + 2048 + w * 512);
    };

    // Q B-frags: col=q, k(d) = mm*16 + hb*8 + e
    bf16x8 bQ[4];
#pragma unroll
    for (int mm = 0; mm < 4; mm++)
        bQ[mm] = *(const bf16x8*)(qbase + (size_t)myq * DD + mm * 16 + hb * 8);

    float m_ = -INFINITY, ls = 0.f;
    f32x16 o[2] = {};

    stage(ks0, 0);
    __syncthreads();
    for (int ci = 0; ci < nc; ci++) {
        int j0 = ks0 + ci * 64;
        int bbuf = ci & 1;
        if (ci + 1 < nc) stage(j0 + 64, bbuf ^ 1);   // async, overlaps compute below
        if (j0 <= qw0 + 31) {
            const u16* Kt = &KV[bbuf][0][0];
            const u16* Vt = &KV[bbuf][1][0];
            f32x16 s[2] = {};
            __builtin_amdgcn_s_setprio(1);
#pragma unroll
            for (int kt = 0; kt < 2; kt++)
#pragma unroll
                for (int mm = 0; mm < 4; mm++) {
                    bf16x8 aK = *(const bf16x8*)(Kt + swz(kt * 32 + q31, mm * 2 + hb));
                    s[kt] = __builtin_amdgcn_mfma_f32_32x32x16_bf16(aK, bQ[mm], s[kt], 0, 0, 0);
                }
            __builtin_amdgcn_s_setprio(0);
            if (j0 + 63 > qw0) {
#pragma unroll
                for (int kt = 0; kt < 2; kt++)
#pragma unroll
                    for (int reg = 0; reg < 16; reg++) {
                        int k = j0 + kt * 32 + (reg & 3) + 8 * (reg >> 2) + 4 * hb;
                        if (k > myq) s[kt][reg] = -INFINITY;
                    }
            }
            float tm = -INFINITY;
#pragma unroll
            for (int kt = 0; kt < 2; kt++)
#pragma unroll
                for (int reg = 0; reg < 16; reg++) tm = fmaxf(tm, s[kt][reg]);
            tm = fmaxf(tm, __shfl_xor(tm, 32, 64));
            // defer-max: only rescale when the new tile max meaningfully exceeds m_
            if (__any(tm > m_ + 8.f)) {
                float mn = fmaxf(m_, tm);
                float f = fexp2(m_ - mn);
                m_ = mn;
                ls *= f;
#pragma unroll
                for (int dt = 0; dt < 2; dt++)
#pragma unroll
                    for (int reg = 0; reg < 16; reg++) o[dt][reg] *= f;
            }
            float rs = 0.f;
#pragma unroll
            for (int kt = 0; kt < 2; kt++)
#pragma unroll
                for (int reg = 0; reg < 16; reg++) {
                    s[kt][reg] = fexp2(s[kt][reg] - m_);
                    rs += s[kt][reg];
                }
            rs += __shfl_xor(rs, 32, 64);
            ls += rs;

            // P^T B-frags + PV
            __builtin_amdgcn_s_setprio(1);
#pragma unroll
            for (int kt = 0; kt < 2; kt++) {
                unsigned W[4][2];
#pragma unroll
                for (int g4 = 0; g4 < 4; g4++) {
                    W[g4][0] = cvtpk(s[kt][4 * g4], s[kt][4 * g4 + 1]);
                    W[g4][1] = cvtpk(s[kt][4 * g4 + 2], s[kt][4 * g4 + 3]);
                }
#pragma unroll
                for (int f2 = 0; f2 < 2; f2++) {
                    unsigned a0 = W[2 * f2][0], b0 = W[2 * f2 + 1][0];
                    unsigned a1 = W[2 * f2][1], b1 = W[2 * f2 + 1][1];
                    asm volatile("v_permlane32_swap_b32 %0, %1" : "+v"(a0), "+v"(b0));
                    asm volatile("v_permlane32_swap_b32 %0, %1" : "+v"(a1), "+v"(b1));
                    union { unsigned u[4]; bf16x8 v; } bp;
                    bp.u[0] = a0; bp.u[1] = a1; bp.u[2] = b0; bp.u[3] = b1;
#pragma unroll
                    for (int dt = 0; dt < 2; dt++) {
                        bf16x8 aV = *(const bf16x8*)(Vt + swz(dt * 32 + q31, kt * 4 + f2 * 2 + hb));
                        o[dt] = __builtin_amdgcn_mfma_f32_32x32x16_bf16(aV, bp.v, o[dt], 0, 0, 0);
                    }
                }
            }
            __builtin_amdgcn_s_setprio(0);
        }
        __syncthreads();   // drains next-chunk loads + guards buffer reuse
    }
    size_t pb = (size_t)(bh * NSEG + sg) * TT;
    float inv = 1.f / ls;
#pragma unroll
    for (int dt = 0; dt < 2; dt++)
#pragma unroll
        for (int g4 = 0; g4 < 4; g4++) {
            u16x4 pk4;
#pragma unroll
            for (int c = 0; c < 4; c++) pk4[c] = f2bf(o[dt][4 * g4 + c] * inv);
            *(u16x4*)(op + (pb + myq) * DD + dt * 32 + 8 * g4 + 4 * hb) = pk4;
        }
    if (hb == 0) {
        mb[pb + myq] = m_;
        lb[pb + myq] = ls;
    }
}

// merge partials (weights computed inline, base-2 domain) + combine with rr branch
__global__ void merge_kernel(const u16* __restrict__ op,
                             const float* __restrict__ mb, const float* __restrict__ lb,
                             const u16* __restrict__ outr, const float* __restrict__ alpha,
                             u16* __restrict__ comb) {
    int i8 = blockIdx.x * blockDim.x + threadIdx.x;
    if (i8 >= M4 * EE / 8) return;
    int bt = i8 / (EE / 8), c8 = i8 - bt * (EE / 8);
    int h = c8 >> 3, d8 = c8 & 7;
    int b = bt >> 11, t = bt & 2047;
    int bh = b * HH + h;
    int ns = (t >> 9) + 1;
    size_t base = (size_t)bh * NSEG * TT + t;
    float M = -INFINITY;
    for (int s = 0; s < ns; s++) M = fmaxf(M, mb[base + (size_t)s * TT]);
    float e[NSEG], L = 0.f;
    for (int s = 0; s < ns; s++) {
        e[s] = lb[base + (size_t)s * TT] * fexp2(mb[base + (size_t)s * TT] - M);
        L += e[s];
    }
    float invL = 1.f / L;
    float acc[8] = {};
    for (int s = 0; s < ns; s++) {
        size_t row = base + (size_t)s * TT;
        float wv = e[s] * invL;
        union { u16 u[8]; bf16x8 v; } pv;
        pv.v = *(const bf16x8*)(op + row * DD + d8 * 8);
#pragma unroll
        for (int ee = 0; ee < 8; ee++) acc[ee] += wv * bf2f(pv.u[ee]);
    }
    float a = 1.f / (1.f + __expf(-alpha[h]));
    union { u16 u[8]; bf16x8 v; } vr, vo;
    vr.v = *(const bf16x8*)(outr + (((size_t)bh * TT + t) * DD + d8 * 8));
#pragma unroll
    for (int ee = 0; ee < 8; ee++)
        vo.u[ee] = f2bf(a * bf2f(vr.u[ee]) + (1.f - a) * acc[ee]);
    ((bf16x8*)comb)[i8] = vo.v;
}

// ---------------------------------------------------------------- output GEMM (m97, BK=64, swizzled LDS)
__global__ __launch_bounds__(256) void gemm_out_kernel(const u16* __restrict__ A,
                                                       const u16* __restrict__ Bt,
                                                       float* __restrict__ C) {
    __shared__ __align__(16) u16 As[128 * 64];
    __shared__ __align__(16) u16 Bs[128 * 64];
    const int K = EE;
    int tid = threadIdx.x;
    int w = tid >> 6, l = tid & 63;
    int lo = l & 15, hi = l >> 4;
    int wm = w >> 1, wn = w & 1;
    int m0 = blockIdx.x * 128;
    int n0 = blockIdx.y * 128;
    int srow = l >> 3;
    int sgx = ((l & 7) ^ (srow & 7)) * 8;

    f32x4 acc[4][4] = {};
    for (int k0 = 0; k0 < K; k0 += 64) {
        __syncthreads();
#pragma unroll
        for (int c4 = 0; c4 < 4; c4++) {
            int c = w * 4 + c4;
            gld_lds16(A + (size_t)(m0 + c * 8 + srow) * K + k0 + sgx, As + c * 512);
            gld_lds16(Bt + (size_t)(n0 + c * 8 + srow) * K + k0 + sgx, Bs + c * 512);
        }
        __syncthreads();
#pragma unroll
        for (int kk = 0; kk < 2; kk++) {
            bf16x8 af[4], bfr[4];
#pragma unroll
            for (int i = 0; i < 4; i++)
                af[i] = *(const bf16x8*)(As + swz(wm * 64 + i * 16 + lo, kk * 4 + hi));
#pragma unroll
            for (int j = 0; j < 4; j++)
                bfr[j] = *(const bf16x8*)(Bs + swz(wn * 64 + j * 16 + lo, kk * 4 + hi));
#pragma unroll
            for (int i = 0; i < 4; i++)
#pragma unroll
                for (int j = 0; j < 4; j++)
                    acc[i][j] = __builtin_amdgcn_mfma_f32_16x16x32_bf16(af[i], bfr[j], acc[i][j], 0, 0, 0);
        }
    }
#pragma unroll
    for (int i = 0; i < 4; i++)
#pragma unroll
        for (int j = 0; j < 4; j++)
#pragma unroll
            for (int r = 0; r < 4; r++) {
                int m = m0 + wm * 64 + i * 16 + hi * 4 + r;
                int n = n0 + wn * 64 + j * 16 + lo;
                C[(size_t)m * EE + n] = acc[i][j][r];
            }
}

// ----------------------------------------------------------------
extern "C" void kernel_launch(void* const* d_in, const int* in_sizes, int n_in,
                              void* d_out, int out_size, void* d_ws, size_t ws_size,
                              hipStream_t stream) {
    const float* x = (const float*)d_in[0];
    const float* wq = (const float*)d_in[1];
    const float* wk = (const float*)d_in[2];
    const float* wv = (const float*)d_in[3];
    const float* wr = (const float*)d_in[4];
    const float* alpha = (const float*)d_in[5];
    const float* wo = (const float*)d_in[6];
    float* out = (float*)d_out;

    char* ws = (char*)d_ws;
    size_t off = 0;
    auto carve = [&](size_t bytes) -> char* {
        char* p = ws + off;
        off += (bytes + 255) & ~(size_t)255;
        return p;
    };
    u16* xb    = (u16*)carve((size_t)M4 * EE * 2);
    u16* wqkvt = (u16*)carve((size_t)NQKV * EE * 2);
    u16* wot   = (u16*)carve((size_t)EE * EE * 2);
    u16* qb    = (u16*)carve((size_t)BH * TT * DD * 2);
    u16* kb    = (u16*)carve((size_t)BH * TT * DD * 2);
    u16* vb    = (u16*)carve((size_t)BH * TT * DD * 2);
    u16* vt    = (u16*)carve((size_t)BH * TT * DD * 2);
    float* xt   = (float*)carve((size_t)BB * EE * TT * 4);
    float* rpbuf= (float*)carve((size_t)48 * BH * TT * 4);
    float* rbuf = (float*)carve((size_t)BH * TT * 4);
    float* rmxp = (float*)carve((size_t)BH * 8 * 4);
    float* Sv   = (float*)carve((size_t)BH * SCH * DD * 4);
    float* Sl   = (float*)carve((size_t)BH * SCH * 4);
    u16* outr  = (u16*)carve((size_t)BH * TT * DD * 2);
    u16* opart = (u16*)carve((size_t)BH * NSEG * TT * DD * 2);
    float* mbuf = (float*)carve((size_t)BH * NSEG * TT * 4);
    float* lbuf = (float*)carve((size_t)BH * NSEG * TT * 4);
    u16* comb  = (u16*)carve((size_t)M4 * EE * 2);

    transpose_all_kernel<<<dim3(TT / 32, EE / 32, 6), 256, 0, stream>>>(
        x, wq, wk, wv, wo, xt, xb, wqkvt, wot);

    dim3 gq(M4 / 128, NQKV / 128);
    gemm_qkv_kernel<<<gq, 256, 0, stream>>>(xb, wqkvt, qb, kb, vb, vt);

    r_partial_kernel<<<dim3(48, 2, 4), 256, 0, stream>>>(xt, wr, rpbuf);
    r_reduce_kernel<<<dim3(BH, 8), 256, 0, stream>>>(rpbuf, rbuf, rmxp);

    scan_part_kernel<<<dim3(SCH, BH), 64, 0, stream>>>(rbuf, rmxp, vb, Sv, Sl);
    scan_out_kernel<<<dim3(SCH, BH), 64, 0, stream>>>(rbuf, rmxp, vb, Sv, Sl, outr);

    flash_kernel<<<dim3(TT / QBLK, NSEG, BH), 256, 0, stream>>>(qb, kb, vt, opart, mbuf, lbuf);
    merge_kernel<<<(M4 * EE / 8 + 255) / 256, 256, 0, stream>>>(opart, mbuf, lbuf, outr, alpha, comb);

    dim3 go(M4 / 128, EE / 128);
    gemm_out_kernel<<<go, 256, 0, stream>>>(comb, wot, out);
}

// Round 15
// 139.668 us; speedup vs baseline: 1.2689x; 1.0653x over previous
//
#include <hip/hip_runtime.h>
#include <math.h>

typedef __bf16 bf16x8 __attribute__((ext_vector_type(8)));
typedef float f32x4 __attribute__((ext_vector_type(4)));
typedef float f32x16 __attribute__((ext_vector_type(16)));
typedef unsigned short u16;
typedef unsigned short u16x4 __attribute__((ext_vector_type(4)));

#define BB 2
#define TT 2048
#define EE 768
#define HH 12
#define DD 64
#define BH (BB*HH)      /* 24 */
#define M4 (BB*TT)      /* 4096 */
#define NQKV (3*EE)     /* 2304 */
#define SCH 16          /* scan chunks (128 t each) */
#define KSEG 512        /* flash split-K segment */
#define NSEG (TT/KSEG)  /* 4 */
#define KVB 64
#define QBLK 128

__device__ __forceinline__ u16 f2bf(float f) {
    union { float f; unsigned u; } v; v.f = f;
    unsigned r = v.u + 0x7FFFu + ((v.u >> 16) & 1u);
    return (u16)(r >> 16);
}
__device__ __forceinline__ float bf2f(u16 u) {
    union { unsigned u; float f; } v; v.u = ((unsigned)u) << 16;
    return v.f;
}
// 2^x via the trans pipe directly
__device__ __forceinline__ float fexp2(float x) {
    float r;
    asm("v_exp_f32 %0, %1" : "=v"(r) : "v"(x));
    return r;
}
// pack two f32 -> u32 of 2 bf16 (lo = a, hi = b), RTNE
__device__ __forceinline__ unsigned cvtpk(float a, float b) {
    unsigned r;
    asm("v_cvt_pk_bf16_f32 %0, %1, %2" : "=v"(r) : "v"(a), "v"(b));
    return r;
}
// u16 index of 8-elem group `grp` in row `row` of a [*,64] u16 LDS tile, XOR-swizzled
__device__ __forceinline__ int swz(int row, int grp) {
    return row * 64 + ((grp ^ (row & 7)) << 3);
}
// async global->LDS, 16B per lane; lds base must be wave-uniform
__device__ __forceinline__ void gld_lds16(const u16* g, u16* l) {
    __builtin_amdgcn_global_load_lds(
        (const __attribute__((address_space(1))) unsigned int*)(const void*)g,
        (__attribute__((address_space(3))) unsigned int*)(void*)l,
        16, 0, 0);
}

// ---------------------------------------------------------------- fused transposes
// z = 0,1: x batch z -> xt (f32 transpose) + xb (bf16 cast)
// z = 2..5: weight z-2 (wq,wk,wv,wo) -> bf16 transpose
__global__ __launch_bounds__(256) void transpose_all_kernel(
    const float* __restrict__ x,
    const float* __restrict__ wq, const float* __restrict__ wk,
    const float* __restrict__ wv, const float* __restrict__ wo,
    float* __restrict__ xt, u16* __restrict__ xb,
    u16* __restrict__ wqkvt, u16* __restrict__ wot)
{
    __shared__ float tile[32][33];
    int z = blockIdx.z;
    int tx = threadIdx.x & 31, ty = threadIdx.x >> 5;
    if (z < 2) {
        int t0 = blockIdx.x * 32, e0 = blockIdx.y * 32, b = z;
#pragma unroll
        for (int i = 0; i < 4; i++) {
            size_t idx = ((size_t)b * TT + t0 + ty + 8 * i) * EE + e0 + tx;
            float v = x[idx];
            tile[ty + 8 * i][tx] = v;
            xb[idx] = f2bf(v);
        }
        __syncthreads();
#pragma unroll
        for (int i = 0; i < 4; i++)
            xt[((size_t)b * EE + e0 + ty + 8 * i) * TT + t0 + tx] = tile[tx][ty + 8 * i];
    } else {
        if (blockIdx.x >= EE / 32) return;
        int zz = z - 2;
        const float* src = (zz == 0) ? wq : (zz == 1) ? wk : (zz == 2) ? wv : wo;
        u16* dst = (zz < 3) ? (wqkvt + (size_t)zz * EE * EE) : wot;
        int n0 = blockIdx.x * 32, k0 = blockIdx.y * 32;
#pragma unroll
        for (int i = 0; i < 4; i++)
            tile[ty + 8 * i][tx] = src[(size_t)(k0 + ty + 8 * i) * EE + n0 + tx];
        __syncthreads();
#pragma unroll
        for (int i = 0; i < 4; i++)
            dst[(size_t)(n0 + ty + 8 * i) * EE + k0 + tx] = f2bf(tile[tx][ty + 8 * i]);
    }
}

// ---------------------------------------------------------------- QKV GEMM (m97, BK=64, swizzled LDS)
// 1D grid 576, XCD-swizzled: each XCD owns 4 A-panels x all 18 B-panels (L2-resident).
// Also writes vt[bh][d][t] directly from the V epilogue.
__global__ __launch_bounds__(256) void gemm_qkv_kernel(
    const u16* __restrict__ A, const u16* __restrict__ Bt,
    u16* __restrict__ qb, u16* __restrict__ kb, u16* __restrict__ vb,
    u16* __restrict__ vt)
{
    __shared__ __align__(16) u16 As[128 * 64];
    __shared__ __align__(16) u16 Bs[128 * 64];
    const int K = EE;
    int id = blockIdx.x;
    int xcd = id & 7, vin = id >> 3;           // vin 0..71
    int bm = xcd * 4 + vin / 18;               // 32 m-tiles
    int bn = vin % 18;                         // 18 n-tiles
    int tid = threadIdx.x;
    int w = tid >> 6, l = tid & 63;
    int lo = l & 15, hi = l >> 4;
    int wm = w >> 1, wn = w & 1;
    int m0 = bm * 128;
    int n0 = bn * 128;
    int srow = l >> 3;
    int sgx = ((l & 7) ^ (srow & 7)) * 8;

    f32x4 acc[4][4] = {};
    for (int k0 = 0; k0 < K; k0 += 64) {
        __syncthreads();
#pragma unroll
        for (int c4 = 0; c4 < 4; c4++) {
            int c = w * 4 + c4;
            gld_lds16(A + (size_t)(m0 + c * 8 + srow) * K + k0 + sgx, As + c * 512);
            gld_lds16(Bt + (size_t)(n0 + c * 8 + srow) * K + k0 + sgx, Bs + c * 512);
        }
        __syncthreads();
#pragma unroll
        for (int kk = 0; kk < 2; kk++) {
            bf16x8 af[4], bfr[4];
#pragma unroll
            for (int i = 0; i < 4; i++)
                af[i] = *(const bf16x8*)(As + swz(wm * 64 + i * 16 + lo, kk * 4 + hi));
#pragma unroll
            for (int j = 0; j < 4; j++)
                bfr[j] = *(const bf16x8*)(Bs + swz(wn * 64 + j * 16 + lo, kk * 4 + hi));
#pragma unroll
            for (int i = 0; i < 4; i++)
#pragma unroll
                for (int j = 0; j < 4; j++)
                    acc[i][j] = __builtin_amdgcn_mfma_f32_16x16x32_bf16(af[i], bfr[j], acc[i][j], 0, 0, 0);
        }
    }
    int sel = n0 / EE;
    int rem0 = n0 - sel * EE;
    u16* dst = (sel == 0) ? qb : (sel == 1) ? kb : vb;
    // q pre-scaled by 1/sqrt(D) * log2(e) so flash can use exp2 directly
    float mul = (sel == 0) ? 0.125f * 1.44269504f : 1.f;
#pragma unroll
    for (int j = 0; j < 4; j++) {
        int h = (rem0 + wn * 64 + j * 16) >> 6;
        int d = (wn * 64 + j * 16 + lo) & 63;
#pragma unroll
        for (int i = 0; i < 4; i++) {
            u16x4 pk4;
#pragma unroll
            for (int r = 0; r < 4; r++) {
                int m = m0 + wm * 64 + i * 16 + hi * 4 + r;
                int b = m >> 11, t = m & 2047;
                u16 val = f2bf(acc[i][j][r] * mul);
                pk4[r] = val;
                dst[((size_t)(b * HH + h) * TT + t) * DD + d] = val;
            }
            if (sel == 2) {
                int mbase = m0 + wm * 64 + i * 16 + hi * 4;
                int b = mbase >> 11, t = mbase & 2047;
                *(u16x4*)(vt + ((size_t)(b * HH + h) * DD + d) * TT + t) = pk4;
            }
        }
    }
}

// ---------------------------------------------------------------- r = scale * x . wr
__global__ __launch_bounds__(256) void r_partial_kernel(
    const float* __restrict__ xt, const float* __restrict__ wr, float* __restrict__ rp) {
    int ech = blockIdx.x;
    int tch = blockIdx.y;
    int hg = blockIdx.z;
    int e0 = ech * 16, h0 = hg * 3;
    int tv = tch * 256 + threadIdx.x;
    const f32x4* xt4 = (const f32x4*)xt;
    const f32x4* wr4 = (const f32x4*)wr;
    f32x4 acc[2][3] = {};
#pragma unroll 4
    for (int e = 0; e < 16; e++) {
        f32x4 x0 = xt4[(size_t)(e0 + e) * 512 + tv];
        f32x4 x1 = xt4[(size_t)(EE + e0 + e) * 512 + tv];
#pragma unroll
        for (int hh = 0; hh < 3; hh++) {
            f32x4 w = wr4[((size_t)(h0 + hh) * EE + e0 + e) * 512 + tv];
            acc[0][hh] += w * x0;
            acc[1][hh] += w * x1;
        }
    }
    f32x4* rp4 = (f32x4*)rp;
#pragma unroll
    for (int b = 0; b < 2; b++)
#pragma unroll
        for (int hh = 0; hh < 3; hh++)
            rp4[((size_t)ech * 24 + b * 12 + h0 + hh) * 512 + tv] = acc[b][hh];
}

// grid (24 bh, 8 t-chunks); writes r + per-chunk max rmxp[bh][8]
__global__ __launch_bounds__(256) void r_reduce_kernel(
    const float* __restrict__ rp, float* __restrict__ r, float* __restrict__ rmxp) {
    int bh = blockIdx.x, tch = blockIdx.y, tid = threadIdx.x;
    int t = tch * 256 + tid;
    float s = 0.f;
#pragma unroll 8
    for (int ech = 0; ech < 48; ech++)
        s += rp[((size_t)(ech * 24 + bh)) * TT + t];
    s *= 0.125f;
    r[(size_t)bh * TT + t] = s;
    __shared__ float sm[256];
    sm[tid] = s; __syncthreads();
    for (int st = 128; st > 0; st >>= 1) {
        if (tid < st) sm[tid] = fmaxf(sm[tid], sm[tid + st]);
        __syncthreads();
    }
    if (tid == 0) rmxp[bh * 8 + tch] = sm[0];
}

// ---------------------------------------------------------------- rr attention = chunked prefix scan
__global__ __launch_bounds__(64) void scan_part_kernel(
    const float* __restrict__ r, const float* __restrict__ rmxp,
    const u16* __restrict__ vb, float* __restrict__ Sv, float* __restrict__ Sl) {
    int c = blockIdx.x, bh = blockIdx.y, d = threadIdx.x;
    float mx = rmxp[bh * 8];
#pragma unroll
    for (int i = 1; i < 8; i++) mx = fmaxf(mx, rmxp[bh * 8 + i]);
    const float* rp = r + (size_t)bh * TT + c * 128;
    const u16* vp = vb + ((size_t)bh * TT + c * 128) * DD + d;
    float accv = 0.f, accl = 0.f;
#pragma unroll 4
    for (int j = 0; j < 128; j++) {
        float w = __expf(rp[j] - mx);
        accv += w * bf2f(vp[(size_t)j * DD]);
        accl += w;
    }
    Sv[((size_t)bh * SCH + c) * DD + d] = accv;
    if (d == 0) Sl[bh * SCH + c] = accl;
}

__global__ __launch_bounds__(64) void scan_out_kernel(
    const float* __restrict__ r, const float* __restrict__ rmxp,
    const u16* __restrict__ vb, const float* __restrict__ Sv, const float* __restrict__ Sl,
    u16* __restrict__ outr) {
    int c = blockIdx.x, bh = blockIdx.y, d = threadIdx.x;
    float mx = rmxp[bh * 8];
#pragma unroll
    for (int i = 1; i < 8; i++) mx = fmaxf(mx, rmxp[bh * 8 + i]);
    float acc = 0.f, accl = 0.f;
    for (int cp = 0; cp < c; cp++) {
        acc += Sv[((size_t)bh * SCH + cp) * DD + d];
        accl += Sl[bh * SCH + cp];
    }
    const float* rp = r + (size_t)bh * TT + c * 128;
    const u16* vp = vb + ((size_t)bh * TT + c * 128) * DD + d;
    u16* op = outr + ((size_t)bh * TT + c * 128) * DD + d;
#pragma unroll 2
    for (int j = 0; j < 128; j++) {
        float w = __expf(rp[j] - mx);
        acc += w * bf2f(vp[(size_t)j * DD]);
        accl += w;
        op[(size_t)j * DD] = f2bf(acc * __builtin_amdgcn_rcpf(accl));
    }
}

// ---------------------------------------------------------------- content flash attention, split-K, 32x32 MFMA
// 1D grid 1536, XCD-swizzled: each XCD owns 3 bh (K/V L2 locality); heavy tiles first per XCD.
// Double-buffered async K/V staging (global_load_lds, pre-swizzled global src).
// S^T = mfma32(K, Q): lane owns q = qw0 + (l&31); softmax in-register; defer-max THR=8.
// P^T B-frags via cvt_pk + permlane32_swap. PV: O^T = mfma32(V^T, P^T).
__global__ __launch_bounds__(256) void flash_kernel(
    const u16* __restrict__ qb, const u16* __restrict__ kb,
    const u16* __restrict__ vt, u16* __restrict__ op,
    float* __restrict__ mb, float* __restrict__ lb) {
    __shared__ __align__(16) u16 KV[2][2][64 * 64];   // [buf][K/V][row*64]
    int id = blockIdx.x;
    int xcd = id & 7, vin = id >> 3;        // vin 0..191
    int bh = xcd * 3 + vin / 64;            // 3 bh per XCD
    int rest = vin & 63;
    int sg = rest >> 4;
    int qt = 15 - (rest & 15);              // heavy tiles first
    int q0 = qt * QBLK;
    int ks0 = sg * KSEG;
    if (ks0 > q0) return;                   // segment has no causal keys for this tile
    int kend = min(ks0 + KSEG, q0 + QBLK);
    int nc = (kend - ks0) >> 6;
    int tid = threadIdx.x, w = tid >> 6, l = tid & 63;
    int q31 = l & 31, hb = l >> 5;
    int qw0 = q0 + w * 32;
    int myq = qw0 + q31;
    const u16* qbase = qb + (size_t)bh * TT * DD;
    const u16* kbase = kb + (size_t)bh * TT * DD;
    const u16* vtb = vt + (size_t)bh * DD * TT;

    int sr0 = w * 8 + (l >> 3);
    int sg8 = (((l & 7) ^ (sr0 & 7)) << 3);
    auto stage = [&](int j0, int bbuf) {
        u16* kd = &KV[bbuf][0][0];
        u16* vd = &KV[bbuf][1][0];
        gld_lds16(kbase + (size_t)(j0 + sr0) * DD + sg8,      kd + w * 512);
        gld_lds16(kbase + (size_t)(j0 + sr0 + 32) * DD + sg8, kd + 2048 + w * 512);
        gld_lds16(vtb + (size_t)sr0 * TT + j0 + sg8,          vd + w * 512);
        gld_lds16(vtb + (size_t)(sr0 + 32) * TT + j0 + sg8,   vd + 2048 + w * 512);
    };

    // Q B-frags: col=q, k(d) = mm*16 + hb*8 + e
    bf16x8 bQ[4];
#pragma unroll
    for (int mm = 0; mm < 4; mm++)
        bQ[mm] = *(const bf16x8*)(qbase + (size_t)myq * DD + mm * 16 + hb * 8);

    float m_ = -INFINITY, ls = 0.f;
    f32x16 o[2] = {};

    stage(ks0, 0);
    __syncthreads();
    for (int ci = 0; ci < nc; ci++) {
        int j0 = ks0 + ci * 64;
        int bbuf = ci & 1;
        if (ci + 1 < nc) stage(j0 + 64, bbuf ^ 1);   // async, overlaps compute below
        if (j0 <= qw0 + 31) {
            const u16* Kt = &KV[bbuf][0][0];
            const u16* Vt = &KV[bbuf][1][0];
            f32x16 s[2] = {};
            __builtin_amdgcn_s_setprio(1);
#pragma unroll
            for (int kt = 0; kt < 2; kt++)
#pragma unroll
                for (int mm = 0; mm < 4; mm++) {
                    bf16x8 aK = *(const bf16x8*)(Kt + swz(kt * 32 + q31, mm * 2 + hb));
                    s[kt] = __builtin_amdgcn_mfma_f32_32x32x16_bf16(aK, bQ[mm], s[kt], 0, 0, 0);
                }
            __builtin_amdgcn_s_setprio(0);
            if (j0 + 63 > qw0) {
#pragma unroll
                for (int kt = 0; kt < 2; kt++)
#pragma unroll
                    for (int reg = 0; reg < 16; reg++) {
                        int k = j0 + kt * 32 + (reg & 3) + 8 * (reg >> 2) + 4 * hb;
                        if (k > myq) s[kt][reg] = -INFINITY;
                    }
            }
            float tm = -INFINITY;
#pragma unroll
            for (int kt = 0; kt < 2; kt++)
#pragma unroll
                for (int reg = 0; reg < 16; reg++) tm = fmaxf(tm, s[kt][reg]);
            tm = fmaxf(tm, __shfl_xor(tm, 32, 64));
            // defer-max: only rescale when the new tile max meaningfully exceeds m_
            if (__any(tm > m_ + 8.f)) {
                float mn = fmaxf(m_, tm);
                float f = fexp2(m_ - mn);
                m_ = mn;
                ls *= f;
#pragma unroll
                for (int dt = 0; dt < 2; dt++)
#pragma unroll
                    for (int reg = 0; reg < 16; reg++) o[dt][reg] *= f;
            }
            float rs = 0.f;
#pragma unroll
            for (int kt = 0; kt < 2; kt++)
#pragma unroll
                for (int reg = 0; reg < 16; reg++) {
                    s[kt][reg] = fexp2(s[kt][reg] - m_);
                    rs += s[kt][reg];
                }
            rs += __shfl_xor(rs, 32, 64);
            ls += rs;

            // P^T B-frags + PV
            __builtin_amdgcn_s_setprio(1);
#pragma unroll
            for (int kt = 0; kt < 2; kt++) {
                unsigned W[4][2];
#pragma unroll
                for (int g4 = 0; g4 < 4; g4++) {
                    W[g4][0] = cvtpk(s[kt][4 * g4], s[kt][4 * g4 + 1]);
                    W[g4][1] = cvtpk(s[kt][4 * g4 + 2], s[kt][4 * g4 + 3]);
                }
#pragma unroll
                for (int f2 = 0; f2 < 2; f2++) {
                    unsigned a0 = W[2 * f2][0], b0 = W[2 * f2 + 1][0];
                    unsigned a1 = W[2 * f2][1], b1 = W[2 * f2 + 1][1];
                    asm volatile("v_permlane32_swap_b32 %0, %1" : "+v"(a0), "+v"(b0));
                    asm volatile("v_permlane32_swap_b32 %0, %1" : "+v"(a1), "+v"(b1));
                    union { unsigned u[4]; bf16x8 v; } bp;
                    bp.u[0] = a0; bp.u[1] = a1; bp.u[2] = b0; bp.u[3] = b1;
#pragma unroll
                    for (int dt = 0; dt < 2; dt++) {
                        bf16x8 aV = *(const bf16x8*)(Vt + swz(dt * 32 + q31, kt * 4 + f2 * 2 + hb));
                        o[dt] = __builtin_amdgcn_mfma_f32_32x32x16_bf16(aV, bp.v, o[dt], 0, 0, 0);
                    }
                }
            }
            __builtin_amdgcn_s_setprio(0);
        }
        __syncthreads();   // drains next-chunk loads + guards buffer reuse
    }
    size_t pb = (size_t)(bh * NSEG + sg) * TT;
    float inv = 1.f / ls;
#pragma unroll
    for (int dt = 0; dt < 2; dt++)
#pragma unroll
        for (int g4 = 0; g4 < 4; g4++) {
            u16x4 pk4;
#pragma unroll
            for (int c = 0; c < 4; c++) pk4[c] = f2bf(o[dt][4 * g4 + c] * inv);
            *(u16x4*)(op + (pb + myq) * DD + dt * 32 + 8 * g4 + 4 * hb) = pk4;
        }
    if (hb == 0) {
        mb[pb + myq] = m_;
        lb[pb + myq] = ls;
    }
}

// merge partials (weights computed inline, base-2 domain) + combine with rr branch
__global__ void merge_kernel(const u16* __restrict__ op,
                             const float* __restrict__ mb, const float* __restrict__ lb,
                             const u16* __restrict__ outr, const float* __restrict__ alpha,
                             u16* __restrict__ comb) {
    int i8 = blockIdx.x * blockDim.x + threadIdx.x;
    if (i8 >= M4 * EE / 8) return;
    int bt = i8 / (EE / 8), c8 = i8 - bt * (EE / 8);
    int h = c8 >> 3, d8 = c8 & 7;
    int b = bt >> 11, t = bt & 2047;
    int bh = b * HH + h;
    int ns = (t >> 9) + 1;
    size_t base = (size_t)bh * NSEG * TT + t;
    float M = -INFINITY;
    for (int s = 0; s < ns; s++) M = fmaxf(M, mb[base + (size_t)s * TT]);
    float e[NSEG], L = 0.f;
    for (int s = 0; s < ns; s++) {
        e[s] = lb[base + (size_t)s * TT] * fexp2(mb[base + (size_t)s * TT] - M);
        L += e[s];
    }
    float invL = 1.f / L;
    float acc[8] = {};
    for (int s = 0; s < ns; s++) {
        size_t row = base + (size_t)s * TT;
        float wv = e[s] * invL;
        union { u16 u[8]; bf16x8 v; } pv;
        pv.v = *(const bf16x8*)(op + row * DD + d8 * 8);
#pragma unroll
        for (int ee = 0; ee < 8; ee++) acc[ee] += wv * bf2f(pv.u[ee]);
    }
    float a = 1.f / (1.f + __expf(-alpha[h]));
    union { u16 u[8]; bf16x8 v; } vr, vo;
    vr.v = *(const bf16x8*)(outr + (((size_t)bh * TT + t) * DD + d8 * 8));
#pragma unroll
    for (int ee = 0; ee < 8; ee++)
        vo.u[ee] = f2bf(a * bf2f(vr.u[ee]) + (1.f - a) * acc[ee]);
    ((bf16x8*)comb)[i8] = vo.v;
}

// ---------------------------------------------------------------- output GEMM (m97, BK=64, swizzled LDS)
// 1D grid 192, XCD-swizzled: each XCD owns 4 A-panels x all 6 B-panels.
__global__ __launch_bounds__(256) void gemm_out_kernel(const u16* __restrict__ A,
                                                       const u16* __restrict__ Bt,
                                                       float* __restrict__ C) {
    __shared__ __align__(16) u16 As[128 * 64];
    __shared__ __align__(16) u16 Bs[128 * 64];
    const int K = EE;
    int id = blockIdx.x;
    int xcd = id & 7, vin = id >> 3;           // vin 0..23
    int bm = xcd * 4 + vin / 6;                // 32 m-tiles
    int bn = vin % 6;                          // 6 n-tiles
    int tid = threadIdx.x;
    int w = tid >> 6, l = tid & 63;
    int lo = l & 15, hi = l >> 4;
    int wm = w >> 1, wn = w & 1;
    int m0 = bm * 128;
    int n0 = bn * 128;
    int srow = l >> 3;
    int sgx = ((l & 7) ^ (srow & 7)) * 8;

    f32x4 acc[4][4] = {};
    for (int k0 = 0; k0 < K; k0 += 64) {
        __syncthreads();
#pragma unroll
        for (int c4 = 0; c4 < 4; c4++) {
            int c = w * 4 + c4;
            gld_lds16(A + (size_t)(m0 + c * 8 + srow) * K + k0 + sgx, As + c * 512);
            gld_lds16(Bt + (size_t)(n0 + c * 8 + srow) * K + k0 + sgx, Bs + c * 512);
        }
        __syncthreads();
#pragma unroll
        for (int kk = 0; kk < 2; kk++) {
            bf16x8 af[4], bfr[4];
#pragma unroll
            for (int i = 0; i < 4; i++)
                af[i] = *(const bf16x8*)(As + swz(wm * 64 + i * 16 + lo, kk * 4 + hi));
#pragma unroll
            for (int j = 0; j < 4; j++)
                bfr[j] = *(const bf16x8*)(Bs + swz(wn * 64 + j * 16 + lo, kk * 4 + hi));
#pragma unroll
            for (int i = 0; i < 4; i++)
#pragma unroll
                for (int j = 0; j < 4; j++)
                    acc[i][j] = __builtin_amdgcn_mfma_f32_16x16x32_bf16(af[i], bfr[j], acc[i][j], 0, 0, 0);
        }
    }
#pragma unroll
    for (int i = 0; i < 4; i++)
#pragma unroll
        for (int j = 0; j < 4; j++)
#pragma unroll
            for (int r = 0; r < 4; r++) {
                int m = m0 + wm * 64 + i * 16 + hi * 4 + r;
                int n = n0 + wn * 64 + j * 16 + lo;
                C[(size_t)m * EE + n] = acc[i][j][r];
            }
}

// ----------------------------------------------------------------
extern "C" void kernel_launch(void* const* d_in, const int* in_sizes, int n_in,
                              void* d_out, int out_size, void* d_ws, size_t ws_size,
                              hipStream_t stream) {
    const float* x = (const float*)d_in[0];
    const float* wq = (const float*)d_in[1];
    const float* wk = (const float*)d_in[2];
    const float* wv = (const float*)d_in[3];
    const float* wr = (const float*)d_in[4];
    const float* alpha = (const float*)d_in[5];
    const float* wo = (const float*)d_in[6];
    float* out = (float*)d_out;

    char* ws = (char*)d_ws;
    size_t off = 0;
    auto carve = [&](size_t bytes) -> char* {
        char* p = ws + off;
        off += (bytes + 255) & ~(size_t)255;
        return p;
    };
    u16* xb    = (u16*)carve((size_t)M4 * EE * 2);
    u16* wqkvt = (u16*)carve((size_t)NQKV * EE * 2);
    u16* wot   = (u16*)carve((size_t)EE * EE * 2);
    u16* qb    = (u16*)carve((size_t)BH * TT * DD * 2);
    u16* kb    = (u16*)carve((size_t)BH * TT * DD * 2);
    u16* vb    = (u16*)carve((size_t)BH * TT * DD * 2);
    u16* vt    = (u16*)carve((size_t)BH * TT * DD * 2);
    float* xt   = (float*)carve((size_t)BB * EE * TT * 4);
    float* rpbuf= (float*)carve((size_t)48 * BH * TT * 4);
    float* rbuf = (float*)carve((size_t)BH * TT * 4);
    float* rmxp = (float*)carve((size_t)BH * 8 * 4);
    float* Sv   = (float*)carve((size_t)BH * SCH * DD * 4);
    float* Sl   = (float*)carve((size_t)BH * SCH * 4);
    u16* outr  = (u16*)carve((size_t)BH * TT * DD * 2);
    u16* opart = (u16*)carve((size_t)BH * NSEG * TT * DD * 2);
    float* mbuf = (float*)carve((size_t)BH * NSEG * TT * 4);
    float* lbuf = (float*)carve((size_t)BH * NSEG * TT * 4);
    u16* comb  = (u16*)carve((size_t)M4 * EE * 2);

    transpose_all_kernel<<<dim3(TT / 32, EE / 32, 6), 256, 0, stream>>>(
        x, wq, wk, wv, wo, xt, xb, wqkvt, wot);

    gemm_qkv_kernel<<<576, 256, 0, stream>>>(xb, wqkvt, qb, kb, vb, vt);

    r_partial_kernel<<<dim3(48, 2, 4), 256, 0, stream>>>(xt, wr, rpbuf);
    r_reduce_kernel<<<dim3(BH, 8), 256, 0, stream>>>(rpbuf, rbuf, rmxp);

    scan_part_kernel<<<dim3(SCH, BH), 64, 0, stream>>>(rbuf, rmxp, vb, Sv, Sl);
    scan_out_kernel<<<dim3(SCH, BH), 64, 0, stream>>>(rbuf, rmxp, vb, Sv, Sl, outr);

    flash_kernel<<<1536, 256, 0, stream>>>(qb, kb, vt, opart, mbuf, lbuf);
    merge_kernel<<<(M4 * EE / 8 + 255) / 256, 256, 0, stream>>>(opart, mbuf, lbuf, outr, alpha, comb);

    gemm_out_kernel<<<192, 256, 0, stream>>>(comb, wot, out);
}